// Round 1
// baseline (335.496 us; speedup 1.0000x reference)
//
#include <hip/hip_runtime.h>
#include <cstdint>
#include <cstddef>

typedef float f4 __attribute__((ext_vector_type(4)));

// Problem constants
// B=4, H=W=128, CH=64 (G=4 x GC=16), K=3, PAD=1, P=9
// padded value map: [B][130][130][64] fp32 = 17,305,600 B
// feat:             [B][128][128][64] fp32 = 16,777,216 B

// ---------------------------------------------------------------------------
// Kernel 0: zero the 1-pixel border ring of vpad (ws is poisoned each call)
// ---------------------------------------------------------------------------
__global__ __launch_bounds__(256) void zero_border_k(float* __restrict__ vpad) {
    int i = blockIdx.x * 256 + threadIdx.x;
    const int total = 4 * 516 * 16;       // B * border_pixels * (64ch/4)
    if (i >= total) return;
    int c4 = i & 15;
    int rest = i >> 4;
    int b = rest / 516;
    int e = rest - b * 516;
    int y, x;
    if (e < 130)      { y = 0;       x = e; }
    else if (e < 260) { y = 129;     x = e - 130; }
    else if (e < 388) { y = e - 259; x = 0; }      // y = 1..128
    else              { y = e - 387; x = 129; }    // y = 1..128
    f4 z = {0.f, 0.f, 0.f, 0.f};
    *(f4*)(vpad + (((size_t)b * 16900 + (size_t)y * 130 + x) * 64 + c4 * 4)) = z;
}

// ---------------------------------------------------------------------------
// Kernel 1: value = x1(NCHW) @ w_value + b_value  -> vpad interior (NHWC, +1 ring)
// block: 256 thr, tile = 64 pixels (x-contig) x 64 out-ch; thread: 4px x 4ch
// ---------------------------------------------------------------------------
__global__ __launch_bounds__(256) void value_proj_k(const float* __restrict__ x1,
                                                    const float* __restrict__ wv,
                                                    const float* __restrict__ bv,
                                                    float* __restrict__ vpad) {
    __shared__ float xs[64][64];   // [ci][px]
    __shared__ float wsh[64][64];  // [ci][c]
    int tid = threadIdx.x;
    int bidx = blockIdx.x;         // ((b*128 + y)*2 + xb)
    int xb = bidx & 1;
    int y  = (bidx >> 1) & 127;
    int b  = bidx >> 8;
    int x0 = xb * 64;

    for (int j = 0; j < 16; j++) {
        int idx = tid + j * 256;
        int ci = idx >> 6, px = idx & 63;
        xs[ci][px]  = x1[(((size_t)b * 64 + ci) * 128 + y) * 128 + x0 + px];
        wsh[ci][px] = wv[idx];
    }
    __syncthreads();

    int c0 = (tid & 15) * 4, p0 = (tid >> 4) * 4;
    f4 bb = *(const f4*)(bv + c0);
    f4 acc[4];
    #pragma unroll
    for (int i = 0; i < 4; i++) acc[i] = bb;

    #pragma unroll
    for (int ci = 0; ci < 64; ci++) {
        f4 w4 = *(f4*)&wsh[ci][c0];
        f4 x4 = *(f4*)&xs[ci][p0];
        #pragma unroll
        for (int i = 0; i < 4; i++) acc[i] += x4[i] * w4;
    }

    #pragma unroll
    for (int i = 0; i < 4; i++) {
        int xp = x0 + p0 + i + 1;                       // padded x
        *(f4*)(vpad + (((size_t)b * 130 + (y + 1)) * 130 + xp) * 64 + c0) = acc[i];
    }
}

// ---------------------------------------------------------------------------
// Kernel 2: feat = gelu(conv3x3(x2 NCHW, w_conv HWIO) + b_conv)  [B,H,W,64]
// block: 256 thr, tile = full row 128px x 64ch; thread: 4px x 8ch
// LDS: one input row slab [64ci][130(+2)] + one (ky,kx) weight tile [64][64]
// ---------------------------------------------------------------------------
__global__ __launch_bounds__(256) void conv_gelu_k(const float* __restrict__ x2,
                                                   const float* __restrict__ wc,
                                                   const float* __restrict__ bc,
                                                   float* __restrict__ feat) {
    __shared__ float xrow[64][132];
    __shared__ float wt[64][64];
    int tid = threadIdx.x;
    int y = blockIdx.x & 127;
    int b = blockIdx.x >> 7;
    int c0 = (tid & 7) * 8, p0 = (tid >> 3) * 4;

    f4 acc[4][2];
    f4 b0 = *(const f4*)(bc + c0), b1 = *(const f4*)(bc + c0 + 4);
    #pragma unroll
    for (int i = 0; i < 4; i++) { acc[i][0] = b0; acc[i][1] = b1; }

    for (int ky = 0; ky < 3; ky++) {
        int yy = y + ky - 1;
        bool yok = (yy >= 0) && (yy < 128);
        __syncthreads();                       // xrow consumers from prev ky done
        for (int j = 0; j < 33; j++) {
            int idx = tid + j * 256;
            if (idx < 8320) {                  // 64ci * 130
                int ci = idx / 130;
                int xx = idx - ci * 130;
                int xg = xx - 1;
                float v = 0.f;
                if (yok && (xg >= 0) && (xg < 128))
                    v = x2[(((size_t)b * 64 + ci) * 128 + yy) * 128 + xg];
                xrow[ci][xx] = v;
            }
        }
        for (int kx = 0; kx < 3; kx++) {
            __syncthreads();                   // wt consumers done / xrow ready
            const f4* wsrc = (const f4*)(wc + (size_t)((ky * 3 + kx) * 64) * 64);
            f4* wdst = (f4*)&wt[0][0];
            #pragma unroll
            for (int j = 0; j < 4; j++) wdst[tid + j * 256] = wsrc[tid + j * 256];
            __syncthreads();
            #pragma unroll
            for (int ci = 0; ci < 64; ci++) {
                float xv0 = xrow[ci][p0 + kx + 0];
                float xv1 = xrow[ci][p0 + kx + 1];
                float xv2 = xrow[ci][p0 + kx + 2];
                float xv3 = xrow[ci][p0 + kx + 3];
                f4 w0 = *(f4*)&wt[ci][c0];
                f4 w1 = *(f4*)&wt[ci][c0 + 4];
                acc[0][0] += xv0 * w0;  acc[0][1] += xv0 * w1;
                acc[1][0] += xv1 * w0;  acc[1][1] += xv1 * w1;
                acc[2][0] += xv2 * w0;  acc[2][1] += xv2 * w1;
                acc[3][0] += xv3 * w0;  acc[3][1] += xv3 * w1;
            }
        }
    }

    const float kA = 0.7978845608028654f, kB = 0.044715f;
    #pragma unroll
    for (int i = 0; i < 4; i++) {
        f4 o[2];
        #pragma unroll
        for (int h = 0; h < 2; h++) {
            #pragma unroll
            for (int j = 0; j < 4; j++) {
                float v = acc[i][h][j];
                float t = tanhf(kA * (v + kB * v * v * v));
                o[h][j] = 0.5f * v * (1.f + t);
            }
        }
        size_t base = (((size_t)b * 128 + y) * 128 + (p0 + i)) * 64 + c0;
        *(f4*)(feat + base)     = o[0];
        *(f4*)(feat + base + 4) = o[1];
    }
}

// ---------------------------------------------------------------------------
// Kernel 3: per-pixel fused heads + softmax + bilinear sampling + out proj
// block: 256 thr = 4 waves, wave = 1 pixel
// ---------------------------------------------------------------------------
__global__ __launch_bounds__(256) void dcn_fused_k(const float* __restrict__ feat,
                                                   const float* __restrict__ vpad,
                                                   const float* __restrict__ wo,
                                                   const float* __restrict__ bo,
                                                   const float* __restrict__ wm,
                                                   const float* __restrict__ bm,
                                                   const float* __restrict__ wout,
                                                   const float* __restrict__ bout,
                                                   float* __restrict__ out) {
    __shared__ float feat_s[4][64];
    __shared__ float off_s[4][72];
    __shared__ float mraw[4][36];
    __shared__ float mexp[4][40];
    __shared__ float msm[4][36];
    __shared__ float samp[4][64];
    int tid = threadIdx.x;
    int w = tid >> 6, lane = tid & 63;
    int pix = blockIdx.x * 4 + w;
    int b = pix >> 14, y = (pix >> 7) & 127, x = pix & 127;

    feat_s[w][lane] = feat[(size_t)pix * 64 + lane];

    // two head outputs per lane: col1 = lane (offset 0..63),
    // col2 = offset 64..71 (lanes 0..7) or mask 0..35 (lanes 8..43)
    float acc1 = bo[lane];
    const float* b2; int s2; float acc2 = 0.f;
    if (lane < 8)       { b2 = wo + 64 + lane; s2 = 72; acc2 = bo[64 + lane]; }
    else if (lane < 44) { b2 = wm + (lane - 8); s2 = 36; acc2 = bm[lane - 8]; }
    else                { b2 = wo + lane;      s2 = 72; }   // dummy
    __syncthreads();

    #pragma unroll 8
    for (int ci = 0; ci < 64; ci++) {
        float f = feat_s[w][ci];
        acc1 = fmaf(f, wo[ci * 72 + lane], acc1);
        acc2 = fmaf(f, b2[ci * s2], acc2);
    }
    off_s[w][lane] = acc1;
    if (lane < 8)       off_s[w][64 + lane] = acc2;
    else if (lane < 44) mraw[w][lane - 8]  = acc2;
    __syncthreads();

    if (lane < 36) {
        int g = lane / 9, bse = g * 9;
        float m = mraw[w][bse];
        #pragma unroll
        for (int j = 1; j < 9; j++) m = fmaxf(m, mraw[w][bse + j]);
        mexp[w][lane] = expf(mraw[w][lane] - m);
    }
    __syncthreads();
    if (lane < 36) {
        int g = lane / 9, bse = g * 9;
        float s = 0.f;
        #pragma unroll
        for (int j = 0; j < 9; j++) s += mexp[w][bse + j];
        msm[w][lane] = mexp[w][lane] / s;
    }
    __syncthreads();

    // sampling: lane = g*16 + cc
    int g = lane >> 4, cc = lane & 15;
    const float* vb = vpad + (size_t)b * 16900 * 64 + g * 16 + cc;
    float accs = 0.f;
    #pragma unroll
    for (int p = 0; p < 9; p++) {
        float ox = off_s[w][g * 18 + p * 2];
        float oy = off_s[w][g * 18 + p * 2 + 1];
        float mv = msm[w][g * 9 + p];
        float sx = (float)(x + (p % 3)) + ox;   // padded coords: x+1 + (p%3-1)
        float sy = (float)(y + (p / 3)) + oy;
        float x0f = floorf(sx), y0f = floorf(sy);
        float fx = sx - x0f, fy = sy - y0f;
        int ix0 = (int)x0f, iy0 = (int)y0f;
        int ix1 = ix0 + 1,  iy1 = iy0 + 1;
        float w00 = (1.f - fx) * (1.f - fy);
        float w01 = fx * (1.f - fy);
        float w10 = (1.f - fx) * fy;
        float w11 = fx * fy;
        bool X0 = (ix0 >= 0) & (ix0 < 130), X1 = (ix1 >= 0) & (ix1 < 130);
        bool Y0 = (iy0 >= 0) & (iy0 < 130), Y1 = (iy1 >= 0) & (iy1 < 130);
        float v00 = 0.f, v01 = 0.f, v10 = 0.f, v11 = 0.f;
        if (Y0) { const float* r = vb + (size_t)iy0 * 130 * 64;
                  if (X0) v00 = r[(size_t)ix0 * 64];
                  if (X1) v01 = r[(size_t)ix1 * 64]; }
        if (Y1) { const float* r = vb + (size_t)iy1 * 130 * 64;
                  if (X0) v10 = r[(size_t)ix0 * 64];
                  if (X1) v11 = r[(size_t)ix1 * 64]; }
        accs += mv * (w00 * v00 + w01 * v01 + w10 * v10 + w11 * v11);
    }
    samp[w][lane] = accs;
    __syncthreads();

    float o = bout[lane];
    #pragma unroll 8
    for (int c = 0; c < 64; c++) o = fmaf(samp[w][c], wout[c * 64 + lane], o);
    out[(((size_t)b * 64 + lane) << 14) + (y << 7) + x] = o;
}

// ---------------------------------------------------------------------------
extern "C" void kernel_launch(void* const* d_in, const int* in_sizes, int n_in,
                              void* d_out, int out_size, void* d_ws, size_t ws_size,
                              hipStream_t stream) {
    const float* x1       = (const float*)d_in[0];
    const float* x2       = (const float*)d_in[1];
    const float* w_value  = (const float*)d_in[2];
    const float* b_value  = (const float*)d_in[3];
    const float* w_conv   = (const float*)d_in[4];
    const float* b_conv   = (const float*)d_in[5];
    const float* w_offset = (const float*)d_in[6];
    const float* b_offset = (const float*)d_in[7];
    const float* w_mask   = (const float*)d_in[8];
    const float* b_mask   = (const float*)d_in[9];
    const float* w_out    = (const float*)d_in[10];
    const float* b_out    = (const float*)d_in[11];

    float* vpad = (float*)d_ws;                              // 17,305,600 B
    float* feat = (float*)((char*)d_ws + 17305600);          // 16,777,216 B
    float* outp = (float*)d_out;

    hipLaunchKernelGGL(zero_border_k, dim3(129),   dim3(256), 0, stream, vpad);
    hipLaunchKernelGGL(value_proj_k,  dim3(1024),  dim3(256), 0, stream,
                       x1, w_value, b_value, vpad);
    hipLaunchKernelGGL(conv_gelu_k,   dim3(512),   dim3(256), 0, stream,
                       x2, w_conv, b_conv, feat);
    hipLaunchKernelGGL(dcn_fused_k,   dim3(16384), dim3(256), 0, stream,
                       feat, vpad, w_offset, b_offset, w_mask, b_mask,
                       w_out, b_out, outp);
}

// Round 2
// 274.182 us; speedup vs baseline: 1.2236x; 1.2236x over previous
//
#include <hip/hip_runtime.h>
#include <cstdint>
#include <cstddef>

typedef float f4 __attribute__((ext_vector_type(4)));

// Problem constants
// B=4, H=W=128, CH=64 (G=4 x GC=16), K=3, PAD=1, P=9
// padded value map: [B][130][130][64] fp32 = 17,305,600 B
// feat:             [B][128][128][64] fp32 = 16,777,216 B

// ---------------------------------------------------------------------------
// Kernel 0: zero the 1-pixel border ring of vpad (ws is poisoned each call)
// ---------------------------------------------------------------------------
__global__ __launch_bounds__(256) void zero_border_k(float* __restrict__ vpad) {
    int i = blockIdx.x * 256 + threadIdx.x;
    const int total = 4 * 516 * 16;       // B * border_pixels * (64ch/4)
    if (i >= total) return;
    int c4 = i & 15;
    int rest = i >> 4;
    int b = rest / 516;
    int e = rest - b * 516;
    int y, x;
    if (e < 130)      { y = 0;       x = e; }
    else if (e < 260) { y = 129;     x = e - 130; }
    else if (e < 388) { y = e - 259; x = 0; }      // y = 1..128
    else              { y = e - 387; x = 129; }    // y = 1..128
    f4 z = {0.f, 0.f, 0.f, 0.f};
    *(f4*)(vpad + (((size_t)b * 16900 + (size_t)y * 130 + x) * 64 + c4 * 4)) = z;
}

// ---------------------------------------------------------------------------
// Kernel 1: value = x1(NCHW) @ w_value + b_value  -> vpad interior (NHWC, +1 ring)
// ---------------------------------------------------------------------------
__global__ __launch_bounds__(256) void value_proj_k(const float* __restrict__ x1,
                                                    const float* __restrict__ wv,
                                                    const float* __restrict__ bv,
                                                    float* __restrict__ vpad) {
    __shared__ float xs[64][64];   // [ci][px]
    __shared__ float wsh[64][64];  // [ci][c]
    int tid = threadIdx.x;
    int bidx = blockIdx.x;         // ((b*128 + y)*2 + xb)
    int xb = bidx & 1;
    int y  = (bidx >> 1) & 127;
    int b  = bidx >> 8;
    int x0 = xb * 64;

    for (int j = 0; j < 16; j++) {
        int idx = tid + j * 256;
        int ci = idx >> 6, px = idx & 63;
        xs[ci][px]  = x1[(((size_t)b * 64 + ci) * 128 + y) * 128 + x0 + px];
        wsh[ci][px] = wv[idx];
    }
    __syncthreads();

    int c0 = (tid & 15) * 4, p0 = (tid >> 4) * 4;
    f4 bb = *(const f4*)(bv + c0);
    f4 acc[4];
    #pragma unroll
    for (int i = 0; i < 4; i++) acc[i] = bb;

    #pragma unroll
    for (int ci = 0; ci < 64; ci++) {
        f4 w4 = *(f4*)&wsh[ci][c0];
        f4 x4 = *(f4*)&xs[ci][p0];
        #pragma unroll
        for (int i = 0; i < 4; i++) acc[i] += x4[i] * w4;
    }

    #pragma unroll
    for (int i = 0; i < 4; i++) {
        int xp = x0 + p0 + i + 1;                       // padded x
        *(f4*)(vpad + (((size_t)b * 130 + (y + 1)) * 130 + xp) * 64 + c0) = acc[i];
    }
}

// ---------------------------------------------------------------------------
// Kernel 2: feat = gelu(conv3x3(x2 NCHW, w_conv HWIO) + b_conv)  [B,H,W,64]
// ---------------------------------------------------------------------------
__global__ __launch_bounds__(256) void conv_gelu_k(const float* __restrict__ x2,
                                                   const float* __restrict__ wc,
                                                   const float* __restrict__ bc,
                                                   float* __restrict__ feat) {
    __shared__ float xrow[64][132];
    __shared__ float wt[64][64];
    int tid = threadIdx.x;
    int y = blockIdx.x & 127;
    int b = blockIdx.x >> 7;
    int c0 = (tid & 7) * 8, p0 = (tid >> 3) * 4;

    f4 acc[4][2];
    f4 b0 = *(const f4*)(bc + c0), b1 = *(const f4*)(bc + c0 + 4);
    #pragma unroll
    for (int i = 0; i < 4; i++) { acc[i][0] = b0; acc[i][1] = b1; }

    for (int ky = 0; ky < 3; ky++) {
        int yy = y + ky - 1;
        bool yok = (yy >= 0) && (yy < 128);
        __syncthreads();                       // xrow consumers from prev ky done
        for (int j = 0; j < 33; j++) {
            int idx = tid + j * 256;
            if (idx < 8320) {                  // 64ci * 130
                int ci = idx / 130;
                int xx = idx - ci * 130;
                int xg = xx - 1;
                float v = 0.f;
                if (yok && (xg >= 0) && (xg < 128))
                    v = x2[(((size_t)b * 64 + ci) * 128 + yy) * 128 + xg];
                xrow[ci][xx] = v;
            }
        }
        for (int kx = 0; kx < 3; kx++) {
            __syncthreads();                   // wt consumers done / xrow ready
            const f4* wsrc = (const f4*)(wc + (size_t)((ky * 3 + kx) * 64) * 64);
            f4* wdst = (f4*)&wt[0][0];
            #pragma unroll
            for (int j = 0; j < 4; j++) wdst[tid + j * 256] = wsrc[tid + j * 256];
            __syncthreads();
            #pragma unroll
            for (int ci = 0; ci < 64; ci++) {
                float xv0 = xrow[ci][p0 + kx + 0];
                float xv1 = xrow[ci][p0 + kx + 1];
                float xv2 = xrow[ci][p0 + kx + 2];
                float xv3 = xrow[ci][p0 + kx + 3];
                f4 w0 = *(f4*)&wt[ci][c0];
                f4 w1 = *(f4*)&wt[ci][c0 + 4];
                acc[0][0] += xv0 * w0;  acc[0][1] += xv0 * w1;
                acc[1][0] += xv1 * w0;  acc[1][1] += xv1 * w1;
                acc[2][0] += xv2 * w0;  acc[2][1] += xv2 * w1;
                acc[3][0] += xv3 * w0;  acc[3][1] += xv3 * w1;
            }
        }
    }

    const float kA = 0.7978845608028654f, kB = 0.044715f;
    #pragma unroll
    for (int i = 0; i < 4; i++) {
        f4 o[2];
        #pragma unroll
        for (int h = 0; h < 2; h++) {
            #pragma unroll
            for (int j = 0; j < 4; j++) {
                float v = acc[i][h][j];
                float t = tanhf(kA * (v + kB * v * v * v));
                o[h][j] = 0.5f * v * (1.f + t);
            }
        }
        size_t base = (((size_t)b * 128 + y) * 128 + (p0 + i)) * 64 + c0;
        *(f4*)(feat + base)     = o[0];
        *(f4*)(feat + base + 4) = o[1];
    }
}

// ---------------------------------------------------------------------------
// Kernel 3 (v2): fused heads + softmax + bilinear sampling + out proj.
// Block = 256 thr = 4 waves; wave owns 8 x-contiguous pixels, ALL wave-private
// (zero __syncthreads). Weight loads amortized 8x via pixel batching; weights
// stay in global (L1/L2-hot). NCHW store via per-wave LDS transpose (32B runs).
// ---------------------------------------------------------------------------
__global__ __launch_bounds__(256, 4) void dcn_fused_v2(const float* __restrict__ feat,
                                                       const float* __restrict__ vpad,
                                                       const float* __restrict__ wo,
                                                       const float* __restrict__ bo,
                                                       const float* __restrict__ wm,
                                                       const float* __restrict__ bm,
                                                       const float* __restrict__ wout,
                                                       const float* __restrict__ bout,
                                                       float* __restrict__ out) {
    __shared__ float feat_s[4][8][64];   // per-wave; reused as transpose buf
    __shared__ float off_s [4][8][72];
    __shared__ float msk_s [4][8][36];   // raw logits -> softmax in place
    __shared__ float samp_s[4][8][64];

    int tid = threadIdx.x;
    int w = tid >> 6, lane = tid & 63;
    int pix0 = blockIdx.x * 32 + w * 8;           // 8 px, same row
    int b = pix0 >> 14, y = (pix0 >> 7) & 127, x0 = pix0 & 127;

    // ---- load feat tile (wave-private, coalesced): lane -> (px=lane/8, ch=(lane%8)*8)
    {
        const float* fp = feat + (size_t)pix0 * 64 + lane * 8;
        f4 fa = *(const f4*)fp;
        f4 fb = *(const f4*)(fp + 4);
        int pj = lane >> 3, ch = (lane & 7) * 8;
        *(f4*)&feat_s[w][pj][ch]     = fa;
        *(f4*)&feat_s[w][pj][ch + 4] = fb;
    }

    // ---- head GEMM: col1 = offset col `lane`; col2 = off 64..71 (lanes 0..7)
    //      or mask 0..35 (lanes 8..43); batched over 8 px
    const float* w2; int s2; float b2v;
    if (lane < 8)       { w2 = wo + 64 + lane; s2 = 72; b2v = bo[64 + lane]; }
    else if (lane < 44) { w2 = wm + (lane - 8); s2 = 36; b2v = bm[lane - 8]; }
    else                { w2 = wo + lane;       s2 = 72; b2v = 0.f; }
    float b1v = bo[lane];

    float acc1[8], acc2[8];
    #pragma unroll
    for (int pj = 0; pj < 8; pj++) { acc1[pj] = b1v; acc2[pj] = b2v; }

    const float* p1 = wo + lane;
    const float* p2 = w2;
    #pragma unroll 4
    for (int c4 = 0; c4 < 16; c4++) {
        float w1v[4], w2v[4];
        #pragma unroll
        for (int jj = 0; jj < 4; jj++) {
            w1v[jj] = p1[jj * 72];
            w2v[jj] = p2[jj * s2];
        }
        p1 += 4 * 72;
        p2 += 4 * s2;
        #pragma unroll
        for (int pj = 0; pj < 8; pj++) {
            f4 fv = *(f4*)&feat_s[w][pj][c4 * 4];
            #pragma unroll
            for (int jj = 0; jj < 4; jj++) {
                acc1[pj] = fmaf(fv[jj], w1v[jj], acc1[pj]);
                acc2[pj] = fmaf(fv[jj], w2v[jj], acc2[pj]);
            }
        }
    }

    #pragma unroll
    for (int pj = 0; pj < 8; pj++) off_s[w][pj][lane] = acc1[pj];
    if (lane < 8) {
        #pragma unroll
        for (int pj = 0; pj < 8; pj++) off_s[w][pj][64 + lane] = acc2[pj];
    } else if (lane < 44) {
        #pragma unroll
        for (int pj = 0; pj < 8; pj++) msk_s[w][pj][lane - 8] = acc2[pj];
    }

    // ---- softmax, lane-parallel: lane<32 -> (px = lane/4, g = lane%4)
    if (lane < 32) {
        int pj = lane >> 2, g = lane & 3;
        float* m = &msk_s[w][pj][g * 9];
        float mx = m[0];
        #pragma unroll
        for (int k = 1; k < 9; k++) mx = fmaxf(mx, m[k]);
        float e[9], s = 0.f;
        #pragma unroll
        for (int k = 0; k < 9; k++) { e[k] = expf(m[k] - mx); s += e[k]; }
        float inv = 1.f / s;
        #pragma unroll
        for (int k = 0; k < 9; k++) m[k] = e[k] * inv;
    }

    // ---- bilinear sampling: lane = g*16 + cc
    {
        int g = lane >> 4, cc = lane & 15;
        const float* vb = vpad + (size_t)b * 16900 * 64 + g * 16 + cc;
        for (int pj = 0; pj < 8; pj++) {
            float accs = 0.f;
            int xpix = x0 + pj;
            #pragma unroll
            for (int p = 0; p < 9; p++) {
                float ox = off_s[w][pj][g * 18 + p * 2];
                float oy = off_s[w][pj][g * 18 + p * 2 + 1];
                float mv = msk_s[w][pj][g * 9 + p];
                float sx = (float)(xpix + (p % 3)) + ox;   // padded coords
                float sy = (float)(y + (p / 3)) + oy;
                float x0f = floorf(sx), y0f = floorf(sy);
                float fx = sx - x0f, fy = sy - y0f;
                int ix0 = (int)x0f, iy0 = (int)y0f;
                int ix1 = ix0 + 1,  iy1 = iy0 + 1;
                float w00 = (1.f - fx) * (1.f - fy);
                float w01 = fx * (1.f - fy);
                float w10 = (1.f - fx) * fy;
                float w11 = fx * fy;
                bool X0 = (ix0 >= 0) & (ix0 < 130), X1 = (ix1 >= 0) & (ix1 < 130);
                bool Y0 = (iy0 >= 0) & (iy0 < 130), Y1 = (iy1 >= 0) & (iy1 < 130);
                float v00 = 0.f, v01 = 0.f, v10 = 0.f, v11 = 0.f;
                if (Y0) { const float* r = vb + (size_t)iy0 * 130 * 64;
                          if (X0) v00 = r[(size_t)ix0 * 64];
                          if (X1) v01 = r[(size_t)ix1 * 64]; }
                if (Y1) { const float* r = vb + (size_t)iy1 * 130 * 64;
                          if (X0) v10 = r[(size_t)ix0 * 64];
                          if (X1) v11 = r[(size_t)ix1 * 64]; }
                accs += mv * (w00 * v00 + w01 * v01 + w10 * v10 + w11 * v11);
            }
            samp_s[w][pj][lane] = accs;
        }
    }

    // ---- output projection, batched over 8 px
    float oacc[8];
    float bov = bout[lane];
    #pragma unroll
    for (int pj = 0; pj < 8; pj++) oacc[pj] = bov;
    const float* pw = wout + lane;
    #pragma unroll 4
    for (int c4 = 0; c4 < 16; c4++) {
        float wv[4];
        #pragma unroll
        for (int jj = 0; jj < 4; jj++) wv[jj] = pw[jj * 64];
        pw += 4 * 64;
        #pragma unroll
        for (int pj = 0; pj < 8; pj++) {
            f4 sv = *(f4*)&samp_s[w][pj][c4 * 4];
            #pragma unroll
            for (int jj = 0; jj < 4; jj++)
                oacc[pj] = fmaf(sv[jj], wv[jj], oacc[pj]);
        }
    }

    // ---- NCHW store via per-wave LDS transpose (reuse feat_s[w])
    #pragma unroll
    for (int pj = 0; pj < 8; pj++) feat_s[w][pj][lane] = oacc[pj];
    float ov[8];
    #pragma unroll
    for (int pj = 0; pj < 8; pj++) ov[pj] = feat_s[w][pj][lane];  // lane = channel
    f4 o0 = {ov[0], ov[1], ov[2], ov[3]};
    f4 o1 = {ov[4], ov[5], ov[6], ov[7]};
    float* op = out + ((size_t)b * 64 + lane) * 16384 + y * 128 + x0;
    *(f4*)op       = o0;
    *(f4*)(op + 4) = o1;
}

// ---------------------------------------------------------------------------
extern "C" void kernel_launch(void* const* d_in, const int* in_sizes, int n_in,
                              void* d_out, int out_size, void* d_ws, size_t ws_size,
                              hipStream_t stream) {
    const float* x1       = (const float*)d_in[0];
    const float* x2       = (const float*)d_in[1];
    const float* w_value  = (const float*)d_in[2];
    const float* b_value  = (const float*)d_in[3];
    const float* w_conv   = (const float*)d_in[4];
    const float* b_conv   = (const float*)d_in[5];
    const float* w_offset = (const float*)d_in[6];
    const float* b_offset = (const float*)d_in[7];
    const float* w_mask   = (const float*)d_in[8];
    const float* b_mask   = (const float*)d_in[9];
    const float* w_out    = (const float*)d_in[10];
    const float* b_out    = (const float*)d_in[11];

    float* vpad = (float*)d_ws;                              // 17,305,600 B
    float* feat = (float*)((char*)d_ws + 17305600);          // 16,777,216 B
    float* outp = (float*)d_out;

    hipLaunchKernelGGL(zero_border_k, dim3(129),  dim3(256), 0, stream, vpad);
    hipLaunchKernelGGL(value_proj_k,  dim3(1024), dim3(256), 0, stream,
                       x1, w_value, b_value, vpad);
    hipLaunchKernelGGL(conv_gelu_k,   dim3(512),  dim3(256), 0, stream,
                       x2, w_conv, b_conv, feat);
    hipLaunchKernelGGL(dcn_fused_v2,  dim3(2048), dim3(256), 0, stream,
                       feat, vpad, w_offset, b_offset, w_mask, b_mask,
                       w_out, b_out, outp);
}

// Round 3
// 235.855 us; speedup vs baseline: 1.4225x; 1.1625x over previous
//
#include <hip/hip_runtime.h>
#include <cstdint>
#include <cstddef>

typedef float f4 __attribute__((ext_vector_type(4)));
typedef float f32x4 __attribute__((ext_vector_type(4)));
typedef short short8 __attribute__((ext_vector_type(8)));
typedef unsigned int u32;
typedef u32 u32x4 __attribute__((ext_vector_type(4)));

// Problem constants: B=4, H=W=128, CH=64 (G=4 x GC=16), K=3, PAD=1, P=9
// ws layout:
//   vpad  fp32 [4][130][130][64]          @ 0          (17,305,600 B)
//   feat  fp32 [4][128][128][64]          @ 17,305,600 (16,777,216 B)
//   x2tp  bf16 [4][130][130][64] swizzled @ 34,082,816 ( 8,652,800 B)
//   wbfT  bf16 [64][576]                  @ 42,735,616 (    73,728 B)

__device__ __forceinline__ unsigned short f2bf(float f) {
    u32 u = __builtin_bit_cast(u32, f);
    return (unsigned short)((u + 0x7FFFu + ((u >> 16) & 1u)) >> 16);
}

// ---------------------------------------------------------------------------
// Kernel 0: zero the 1-pixel border ring of vpad (ws is poisoned each call)
// ---------------------------------------------------------------------------
__global__ __launch_bounds__(256) void zero_border_k(float* __restrict__ vpad) {
    int i = blockIdx.x * 256 + threadIdx.x;
    const int total = 4 * 516 * 16;
    if (i >= total) return;
    int c4 = i & 15;
    int rest = i >> 4;
    int b = rest / 516;
    int e = rest - b * 516;
    int y, x;
    if (e < 130)      { y = 0;       x = e; }
    else if (e < 260) { y = 129;     x = e - 130; }
    else if (e < 388) { y = e - 259; x = 0; }
    else              { y = e - 387; x = 129; }
    f4 z = {0.f, 0.f, 0.f, 0.f};
    *(f4*)(vpad + (((size_t)b * 16900 + (size_t)y * 130 + x) * 64 + c4 * 4)) = z;
}

// ---------------------------------------------------------------------------
// Kernel 0b: zero the border ring of x2tp (bf16, 128 B per pixel)
// ---------------------------------------------------------------------------
__global__ __launch_bounds__(256) void x2ring_k(char* __restrict__ x2tp) {
    int i = blockIdx.x * 256 + threadIdx.x;
    const int total = 4 * 516 * 8;
    if (i >= total) return;
    int c8 = i & 7;
    int rest = i >> 3;
    int b = rest / 516;
    int e = rest - b * 516;
    int y, x;
    if (e < 130)      { y = 0;       x = e; }
    else if (e < 260) { y = 129;     x = e - 130; }
    else if (e < 388) { y = e - 259; x = 0; }
    else              { y = e - 387; x = 129; }
    u32x4 z = {0u, 0u, 0u, 0u};
    *(u32x4*)(x2tp + ((size_t)b * 16900 + (size_t)y * 130 + x) * 128 + c8 * 16) = z;
}

// ---------------------------------------------------------------------------
// Kernel 0c: w_conv [576k][64c] fp32 -> wbfT [64c][576k] bf16 (B-frag layout)
// grid 72 x 256: each thread packs 2 consecutive k for one c
// ---------------------------------------------------------------------------
__global__ __launch_bounds__(256) void wprep_k(const float* __restrict__ wc,
                                               char* __restrict__ wbfT) {
    int i = blockIdx.x * 256 + threadIdx.x;     // 18432 items
    int c = i / 288, kp = i - c * 288;
    int k = kp << 1;
    float f0 = wc[(size_t)k * 64 + c];
    float f1 = wc[(size_t)(k + 1) * 64 + c];
    u32 pk = (u32)f2bf(f0) | ((u32)f2bf(f1) << 16);
    *(u32*)(wbfT + (size_t)c * 1152 + kp * 4) = pk;
}

// ---------------------------------------------------------------------------
// Kernel 0d: x2 NCHW fp32 -> x2tp padded NHWC bf16, octet-XOR-swizzled.
// Octet g of pixel (padded) xp stored at slot g ^ (xp & 7) within the 128 B
// pixel record, so a LINEAR global_load_lds produces the swizzled LDS image.
// One block per (b, y): LDS transpose 64ci x 128x.
// ---------------------------------------------------------------------------
__global__ __launch_bounds__(256) void x2prep_k(const float* __restrict__ x2,
                                                char* __restrict__ x2tp) {
    __shared__ u32 tr[4096];                    // 16 KB, swizzled [x][ci] bf16
    int t = threadIdx.x;
    int y = blockIdx.x & 127, b = blockIdx.x >> 7;
    const float* xb = x2 + (size_t)b * 64 * 16384 + (size_t)y * 128;
    #pragma unroll 4
    for (int j = 0; j < 16; j++) {
        int idx = t + (j << 8);                 // 32 cip x 128 x
        int x = idx & 127, cip = idx >> 7;
        int ci = cip << 1;
        float f0 = xb[(size_t)ci * 16384 + x];
        float f1 = xb[(size_t)(ci + 1) * 16384 + x];
        u32 pk = (u32)f2bf(f0) | ((u32)f2bf(f1) << 16);
        int key = (x + 1) & 7;                  // swizzle on PADDED x
        int byt = x * 128 + (((ci >> 3) ^ key) << 4) + (ci & 7) * 2;
        tr[byt >> 2] = pk;
    }
    __syncthreads();
    const u32x4* src = (const u32x4*)tr;
    u32x4* dst = (u32x4*)(x2tp + ((size_t)(b * 130 + y + 1) * 130 + 1) * 128);
    #pragma unroll
    for (int j = 0; j < 4; j++) {
        int c = t + (j << 8);
        dst[c] = src[c];
    }
}

// ---------------------------------------------------------------------------
// Kernel 1: value = x1(NCHW) @ w_value + b_value -> vpad interior (fp32)
// ---------------------------------------------------------------------------
__global__ __launch_bounds__(256) void value_proj_k(const float* __restrict__ x1,
                                                    const float* __restrict__ wv,
                                                    const float* __restrict__ bv,
                                                    float* __restrict__ vpad) {
    __shared__ float xs[64][64];
    __shared__ float wsh[64][64];
    int tid = threadIdx.x;
    int bidx = blockIdx.x;
    int xb = bidx & 1;
    int y  = (bidx >> 1) & 127;
    int b  = bidx >> 8;
    int x0 = xb * 64;

    for (int j = 0; j < 16; j++) {
        int idx = tid + j * 256;
        int ci = idx >> 6, px = idx & 63;
        xs[ci][px]  = x1[(((size_t)b * 64 + ci) * 128 + y) * 128 + x0 + px];
        wsh[ci][px] = wv[idx];
    }
    __syncthreads();

    int c0 = (tid & 15) * 4, p0 = (tid >> 4) * 4;
    f4 bb = *(const f4*)(bv + c0);
    f4 acc[4];
    #pragma unroll
    for (int i = 0; i < 4; i++) acc[i] = bb;

    #pragma unroll
    for (int ci = 0; ci < 64; ci++) {
        f4 w4 = *(f4*)&wsh[ci][c0];
        f4 x4 = *(f4*)&xs[ci][p0];
        #pragma unroll
        for (int i = 0; i < 4; i++) acc[i] += x4[i] * w4;
    }

    #pragma unroll
    for (int i = 0; i < 4; i++) {
        int xp = x0 + p0 + i + 1;
        *(f4*)(vpad + (((size_t)b * 130 + (y + 1)) * 130 + xp) * 64 + c0) = acc[i];
    }
}

// ---------------------------------------------------------------------------
// Kernel 2 (v3): conv3x3 + GELU via bf16 MFMA implicit GEMM.
// Block = 256 thr / 4 waves = 64 px x 64 out-ch; wave = 16 px x 64 ch.
// K = 576 -> 18 steps of 32 (tap-major, ci-minor). A from swizzled LDS slab
// (staged with global_load_lds from pre-swizzled x2tp); B from L2 (wbfT).
// ---------------------------------------------------------------------------
__global__ __launch_bounds__(256, 4) void conv_mfma_k(const char* __restrict__ x2tp,
                                                      const char* __restrict__ wbfT,
                                                      const float* __restrict__ bc,
                                                      float* __restrict__ feat) {
    __shared__ char slab[3 * 8448];            // 3 rows x 66 px x 128 B
    int tid = threadIdx.x;
    int l = tid & 63, w = tid >> 6;
    int bidx = blockIdx.x;
    int xb = bidx & 1, y = (bidx >> 1) & 127, b = bidx >> 8;
    int x0 = xb << 6;

    // stage: rows (padded) y..y+2, px x0..x0+65 -> 3 x 8448 B, linear dest
    const char* gr = x2tp + ((size_t)(b * 130 + y) * 130 + x0) * 128;
    for (int q = w; q < 27; q += 4) {
        int r = q / 9, cq = q - r * 9;
        int nb = (cq < 8) ? 1024 : 256;
        if (l * 16 < nb) {
            const char* g = gr + (size_t)r * (130 * 128) + cq * 1024 + l * 16;
            char* p = slab + r * 8448 + cq * 1024 + l * 16;
            __builtin_amdgcn_global_load_lds(
                (const __attribute__((address_space(1))) u32*)g,
                (__attribute__((address_space(3))) u32*)p, 16, 0, 0);
        }
    }
    __syncthreads();

    int m0 = w << 4;
    int r16 = l & 15, g16 = l >> 4;
    f32x4 acc[4] = {{0.f,0.f,0.f,0.f},{0.f,0.f,0.f,0.f},
                    {0.f,0.f,0.f,0.f},{0.f,0.f,0.f,0.f}};
    const char* wb = wbfT + (size_t)r16 * 1152 + g16 * 16;

    #pragma unroll
    for (int s = 0; s < 18; s++) {
        const int t9 = s >> 1;
        const int ky = t9 / 3, kx = t9 - ky * 3;
        const int ci0g = (s & 1) * 4;          // ci0/8
        int x_sl = m0 + r16 + kx;              // 0..65
        int go = (ci0g + g16) ^ (x_sl & 7);    // swizzled octet slot
        short8 a = *(const short8*)(slab + ky * 8448 + x_sl * 128 + go * 16);
        #pragma unroll
        for (int cb = 0; cb < 4; cb++) {
            short8 bf = *(const short8*)(wb + (size_t)cb * (16 * 1152) + s * 64);
            acc[cb] = __builtin_amdgcn_mfma_f32_16x16x32_bf16(a, bf, acc[cb], 0, 0, 0);
        }
    }

    // epilogue: bias + tanh-GELU (exp-based), store fp32 feat NHWC
    const float kA = 0.7978845608028654f, kB = 0.044715f;
    float* fp = feat + ((size_t)b * 16384 + (size_t)y * 128 + x0 + m0) * 64;
    #pragma unroll
    for (int cb = 0; cb < 4; cb++) {
        float bcv = bc[cb * 16 + r16];
        #pragma unroll
        for (int j = 0; j < 4; j++) {
            float v = acc[cb][j] + bcv;
            float z = kA * (v + kB * v * v * v);
            float e = __expf(2.f * z);
            float th = 1.f - 2.f / (e + 1.f);
            float o = 0.5f * v * (1.f + th);
            fp[(size_t)(g16 * 4 + j) * 64 + cb * 16 + r16] = o;
        }
    }
}

// ---------------------------------------------------------------------------
// Kernel 3: fused heads + softmax + bilinear sampling + out proj (wave-private)
// ---------------------------------------------------------------------------
__global__ __launch_bounds__(256, 4) void dcn_fused_v2(const float* __restrict__ feat,
                                                       const float* __restrict__ vpad,
                                                       const float* __restrict__ wo,
                                                       const float* __restrict__ bo,
                                                       const float* __restrict__ wm,
                                                       const float* __restrict__ bm,
                                                       const float* __restrict__ wout,
                                                       const float* __restrict__ bout,
                                                       float* __restrict__ out) {
    __shared__ float feat_s[4][8][64];
    __shared__ float off_s [4][8][72];
    __shared__ float msk_s [4][8][36];
    __shared__ float samp_s[4][8][64];

    int tid = threadIdx.x;
    int w = tid >> 6, lane = tid & 63;
    int pix0 = blockIdx.x * 32 + w * 8;
    int b = pix0 >> 14, y = (pix0 >> 7) & 127, x0 = pix0 & 127;

    {
        const float* fp = feat + (size_t)pix0 * 64 + lane * 8;
        f4 fa = *(const f4*)fp;
        f4 fb = *(const f4*)(fp + 4);
        int pj = lane >> 3, ch = (lane & 7) * 8;
        *(f4*)&feat_s[w][pj][ch]     = fa;
        *(f4*)&feat_s[w][pj][ch + 4] = fb;
    }

    const float* w2; int s2; float b2v;
    if (lane < 8)       { w2 = wo + 64 + lane; s2 = 72; b2v = bo[64 + lane]; }
    else if (lane < 44) { w2 = wm + (lane - 8); s2 = 36; b2v = bm[lane - 8]; }
    else                { w2 = wo + lane;       s2 = 72; b2v = 0.f; }
    float b1v = bo[lane];

    float acc1[8], acc2[8];
    #pragma unroll
    for (int pj = 0; pj < 8; pj++) { acc1[pj] = b1v; acc2[pj] = b2v; }

    const float* p1 = wo + lane;
    const float* p2 = w2;
    #pragma unroll 4
    for (int c4 = 0; c4 < 16; c4++) {
        float w1v[4], w2v[4];
        #pragma unroll
        for (int jj = 0; jj < 4; jj++) {
            w1v[jj] = p1[jj * 72];
            w2v[jj] = p2[jj * s2];
        }
        p1 += 4 * 72;
        p2 += 4 * s2;
        #pragma unroll
        for (int pj = 0; pj < 8; pj++) {
            f4 fv = *(f4*)&feat_s[w][pj][c4 * 4];
            #pragma unroll
            for (int jj = 0; jj < 4; jj++) {
                acc1[pj] = fmaf(fv[jj], w1v[jj], acc1[pj]);
                acc2[pj] = fmaf(fv[jj], w2v[jj], acc2[pj]);
            }
        }
    }

    #pragma unroll
    for (int pj = 0; pj < 8; pj++) off_s[w][pj][lane] = acc1[pj];
    if (lane < 8) {
        #pragma unroll
        for (int pj = 0; pj < 8; pj++) off_s[w][pj][64 + lane] = acc2[pj];
    } else if (lane < 44) {
        #pragma unroll
        for (int pj = 0; pj < 8; pj++) msk_s[w][pj][lane - 8] = acc2[pj];
    }

    if (lane < 32) {
        int pj = lane >> 2, g = lane & 3;
        float* m = &msk_s[w][pj][g * 9];
        float mx = m[0];
        #pragma unroll
        for (int k = 1; k < 9; k++) mx = fmaxf(mx, m[k]);
        float e[9], s = 0.f;
        #pragma unroll
        for (int k = 0; k < 9; k++) { e[k] = expf(m[k] - mx); s += e[k]; }
        float inv = 1.f / s;
        #pragma unroll
        for (int k = 0; k < 9; k++) m[k] = e[k] * inv;
    }

    {
        int g = lane >> 4, cc = lane & 15;
        const float* vb = vpad + (size_t)b * 16900 * 64 + g * 16 + cc;
        for (int pj = 0; pj < 8; pj++) {
            float accs = 0.f;
            int xpix = x0 + pj;
            #pragma unroll
            for (int p = 0; p < 9; p++) {
                float ox = off_s[w][pj][g * 18 + p * 2];
                float oy = off_s[w][pj][g * 18 + p * 2 + 1];
                float mv = msk_s[w][pj][g * 9 + p];
                float sx = (float)(xpix + (p % 3)) + ox;
                float sy = (float)(y + (p / 3)) + oy;
                float x0f = floorf(sx), y0f = floorf(sy);
                float fx = sx - x0f, fy = sy - y0f;
                int ix0 = (int)x0f, iy0 = (int)y0f;
                int ix1 = ix0 + 1,  iy1 = iy0 + 1;
                float w00 = (1.f - fx) * (1.f - fy);
                float w01 = fx * (1.f - fy);
                float w10 = (1.f - fx) * fy;
                float w11 = fx * fy;
                bool X0 = (ix0 >= 0) & (ix0 < 130), X1 = (ix1 >= 0) & (ix1 < 130);
                bool Y0 = (iy0 >= 0) & (iy0 < 130), Y1 = (iy1 >= 0) & (iy1 < 130);
                float v00 = 0.f, v01 = 0.f, v10 = 0.f, v11 = 0.f;
                if (Y0) { const float* r = vb + (size_t)iy0 * 130 * 64;
                          if (X0) v00 = r[(size_t)ix0 * 64];
                          if (X1) v01 = r[(size_t)ix1 * 64]; }
                if (Y1) { const float* r = vb + (size_t)iy1 * 130 * 64;
                          if (X0) v10 = r[(size_t)ix0 * 64];
                          if (X1) v11 = r[(size_t)ix1 * 64]; }
                accs += mv * (w00 * v00 + w01 * v01 + w10 * v10 + w11 * v11);
            }
            samp_s[w][pj][lane] = accs;
        }
    }

    float oacc[8];
    float bov = bout[lane];
    #pragma unroll
    for (int pj = 0; pj < 8; pj++) oacc[pj] = bov;
    const float* pw = wout + lane;
    #pragma unroll 4
    for (int c4 = 0; c4 < 16; c4++) {
        float wv[4];
        #pragma unroll
        for (int jj = 0; jj < 4; jj++) wv[jj] = pw[jj * 64];
        pw += 4 * 64;
        #pragma unroll
        for (int pj = 0; pj < 8; pj++) {
            f4 sv = *(f4*)&samp_s[w][pj][c4 * 4];
            #pragma unroll
            for (int jj = 0; jj < 4; jj++)
                oacc[pj] = fmaf(sv[jj], wv[jj], oacc[pj]);
        }
    }

    #pragma unroll
    for (int pj = 0; pj < 8; pj++) feat_s[w][pj][lane] = oacc[pj];
    float ov[8];
    #pragma unroll
    for (int pj = 0; pj < 8; pj++) ov[pj] = feat_s[w][pj][lane];
    f4 o0 = {ov[0], ov[1], ov[2], ov[3]};
    f4 o1 = {ov[4], ov[5], ov[6], ov[7]};
    float* op = out + ((size_t)b * 64 + lane) * 16384 + y * 128 + x0;
    *(f4*)op       = o0;
    *(f4*)(op + 4) = o1;
}

// ---------------------------------------------------------------------------
extern "C" void kernel_launch(void* const* d_in, const int* in_sizes, int n_in,
                              void* d_out, int out_size, void* d_ws, size_t ws_size,
                              hipStream_t stream) {
    const float* x1       = (const float*)d_in[0];
    const float* x2       = (const float*)d_in[1];
    const float* w_value  = (const float*)d_in[2];
    const float* b_value  = (const float*)d_in[3];
    const float* w_conv   = (const float*)d_in[4];
    const float* b_conv   = (const float*)d_in[5];
    const float* w_offset = (const float*)d_in[6];
    const float* b_offset = (const float*)d_in[7];
    const float* w_mask   = (const float*)d_in[8];
    const float* b_mask   = (const float*)d_in[9];
    const float* w_out    = (const float*)d_in[10];
    const float* b_out    = (const float*)d_in[11];

    float* vpad = (float*)d_ws;
    float* feat = (float*)((char*)d_ws + 17305600);
    char*  x2tp = (char*)d_ws + 34082816;
    char*  wbfT = (char*)d_ws + 42735616;
    float* outp = (float*)d_out;

    hipLaunchKernelGGL(zero_border_k, dim3(129),  dim3(256), 0, stream, vpad);
    hipLaunchKernelGGL(x2ring_k,      dim3(65),   dim3(256), 0, stream, x2tp);
    hipLaunchKernelGGL(wprep_k,       dim3(72),   dim3(256), 0, stream, w_conv, wbfT);
    hipLaunchKernelGGL(x2prep_k,      dim3(512),  dim3(256), 0, stream, x2, x2tp);
    hipLaunchKernelGGL(value_proj_k,  dim3(1024), dim3(256), 0, stream,
                       x1, w_value, b_value, vpad);
    hipLaunchKernelGGL(conv_mfma_k,   dim3(1024), dim3(256), 0, stream,
                       x2tp, wbfT, b_conv, feat);
    hipLaunchKernelGGL(dcn_fused_v2,  dim3(2048), dim3(256), 0, stream,
                       feat, vpad, w_offset, b_offset, w_mask, b_mask,
                       w_out, b_out, outp);
}

// Round 4
// 225.238 us; speedup vs baseline: 1.4895x; 1.0471x over previous
//
#include <hip/hip_runtime.h>
#include <cstdint>
#include <cstddef>

typedef float f4 __attribute__((ext_vector_type(4)));
typedef float f2 __attribute__((ext_vector_type(2)));
typedef float f32x4 __attribute__((ext_vector_type(4)));
typedef short short8 __attribute__((ext_vector_type(8)));
typedef unsigned int u32;
typedef unsigned short u16;
typedef u32 u32x4 __attribute__((ext_vector_type(4)));

// Problem: B=4, H=W=128, CH=64 (G=4 x GC=16), K=3, PAD=1, P=9
// ws layout:
//   vpad  fp32 [4][132][132][64] (2-ring zero) @ 0          17,842,176 B
//   featb bf16 [4][16384][64]                  @ 17,842,176  8,388,608 B
//   x2tp  bf16 [4][130][130][64] swizzled      @ 26,230,784  8,652,800 B
//   wbfT  bf16 [64][576]                       @ 34,883,584     73,728 B
//   whead bf16 [112 cols][64 k]                @ 34,957,312     14,336 B

__device__ __forceinline__ u16 f2bf(float f) {
    u32 u = __builtin_bit_cast(u32, f);
    return (u16)((u + 0x7FFFu + ((u >> 16) & 1u)) >> 16);
}

// ---------------------------------------------------------------------------
// Kernel A: zero 2-px ring of vpad + 1-px ring of x2tp (ws poisoned each call)
// grid 325: blocks [0,260) -> vpad, [260,325) -> x2tp
// ---------------------------------------------------------------------------
__global__ __launch_bounds__(256) void prep_zero_k(float* __restrict__ vpad,
                                                   char* __restrict__ x2tp) {
    int blk = blockIdx.x;
    if (blk < 260) {
        int i = blk * 256 + threadIdx.x;        // 4b x 1040px x 16 chunks
        if (i >= 66560) return;
        int c4 = i & 15;
        int rest = i >> 4;
        int b = rest / 1040;
        int e = rest - b * 1040;
        int y, x;
        if (e < 132)      { y = 0;   x = e; }
        else if (e < 264) { y = 1;   x = e - 132; }
        else if (e < 396) { y = 130; x = e - 264; }
        else if (e < 528) { y = 131; x = e - 396; }
        else { int e2 = e - 528; y = 2 + (e2 >> 2); int m = e2 & 3;
               x = (m < 2) ? m : m + 128; }
        f4 z = {0.f, 0.f, 0.f, 0.f};
        *(f4*)(vpad + (((size_t)b * 17424 + (size_t)y * 132 + x) * 64 + c4 * 4)) = z;
    } else {
        int i = (blk - 260) * 256 + threadIdx.x;  // 4b x 516px x 8 chunks
        if (i >= 16512) return;
        int c8 = i & 7;
        int rest = i >> 3;
        int b = rest / 516;
        int e = rest - b * 516;
        int y, x;
        if (e < 130)      { y = 0;       x = e; }
        else if (e < 260) { y = 129;     x = e - 130; }
        else if (e < 388) { y = e - 259; x = 0; }
        else              { y = e - 387; x = 129; }
        u32x4 z = {0u, 0u, 0u, 0u};
        *(u32x4*)(x2tp + ((size_t)b * 16900 + (size_t)y * 130 + x) * 128 + c8 * 16) = z;
    }
}

// ---------------------------------------------------------------------------
// Kernel B: weight prep. blocks [0,72): w_conv -> wbfT [64c][576k] bf16.
// blocks [72,100): wo||wm||0 -> whead [112 col][64 k] bf16.
// ---------------------------------------------------------------------------
__global__ __launch_bounds__(256) void prep_w_k(const float* __restrict__ wc,
                                                const float* __restrict__ wo,
                                                const float* __restrict__ wm,
                                                char* __restrict__ wbfT,
                                                char* __restrict__ whead) {
    int blk = blockIdx.x;
    if (blk < 72) {
        int i = blk * 256 + threadIdx.x;        // 18432 items
        int c = i / 288, kp = i - c * 288;
        int k = kp << 1;
        float f0 = wc[(size_t)k * 64 + c];
        float f1 = wc[(size_t)(k + 1) * 64 + c];
        u32 pk = (u32)f2bf(f0) | ((u32)f2bf(f1) << 16);
        *(u32*)(wbfT + (size_t)c * 1152 + kp * 4) = pk;
    } else {
        int i = (blk - 72) * 256 + threadIdx.x; // 7168 items
        int k = i & 63, col = i >> 6;           // col 0..111
        float v = 0.f;
        if (col < 72)       v = wo[(size_t)k * 72 + col];
        else if (col < 108) v = wm[(size_t)k * 36 + col - 72];
        *(u16*)(whead + (size_t)(col * 64 + k) * 2) = f2bf(v);
    }
}

// ---------------------------------------------------------------------------
// Kernel C: x2 NCHW fp32 -> x2tp padded NHWC bf16, octet-XOR-swizzled.
// ---------------------------------------------------------------------------
__global__ __launch_bounds__(256) void x2prep_k(const float* __restrict__ x2,
                                                char* __restrict__ x2tp) {
    __shared__ u32 tr[4096];
    int t = threadIdx.x;
    int y = blockIdx.x & 127, b = blockIdx.x >> 7;
    const float* xb = x2 + (size_t)b * 64 * 16384 + (size_t)y * 128;
    #pragma unroll 4
    for (int j = 0; j < 16; j++) {
        int idx = t + (j << 8);
        int x = idx & 127, cip = idx >> 7;
        int ci = cip << 1;
        float f0 = xb[(size_t)ci * 16384 + x];
        float f1 = xb[(size_t)(ci + 1) * 16384 + x];
        u32 pk = (u32)f2bf(f0) | ((u32)f2bf(f1) << 16);
        int key = (x + 1) & 7;
        int byt = x * 128 + (((ci >> 3) ^ key) << 4) + (ci & 7) * 2;
        tr[byt >> 2] = pk;
    }
    __syncthreads();
    const u32x4* src = (const u32x4*)tr;
    u32x4* dst = (u32x4*)(x2tp + ((size_t)(b * 130 + y + 1) * 130 + 1) * 128);
    #pragma unroll
    for (int j = 0; j < 4; j++) {
        int c = t + (j << 8);
        dst[c] = src[c];
    }
}

// ---------------------------------------------------------------------------
// Kernel D: value = x1(NCHW) @ w_value + b_value -> vpad interior (fp32)
// interior now at [y+2][x+2] of the 132x132 map
// ---------------------------------------------------------------------------
__global__ __launch_bounds__(256) void value_proj_k(const float* __restrict__ x1,
                                                    const float* __restrict__ wv,
                                                    const float* __restrict__ bv,
                                                    float* __restrict__ vpad) {
    __shared__ float xs[64][64];
    __shared__ float wsh[64][64];
    int tid = threadIdx.x;
    int bidx = blockIdx.x;
    int xb = bidx & 1;
    int y  = (bidx >> 1) & 127;
    int b  = bidx >> 8;
    int x0 = xb * 64;

    for (int j = 0; j < 16; j++) {
        int idx = tid + j * 256;
        int ci = idx >> 6, px = idx & 63;
        xs[ci][px]  = x1[(((size_t)b * 64 + ci) * 128 + y) * 128 + x0 + px];
        wsh[ci][px] = wv[idx];
    }
    __syncthreads();

    int c0 = (tid & 15) * 4, p0 = (tid >> 4) * 4;
    f4 bb = *(const f4*)(bv + c0);
    f4 acc[4];
    #pragma unroll
    for (int i = 0; i < 4; i++) acc[i] = bb;

    #pragma unroll
    for (int ci = 0; ci < 64; ci++) {
        f4 w4 = *(f4*)&wsh[ci][c0];
        f4 x4 = *(f4*)&xs[ci][p0];
        #pragma unroll
        for (int i = 0; i < 4; i++) acc[i] += x4[i] * w4;
    }

    #pragma unroll
    for (int i = 0; i < 4; i++) {
        int xp = x0 + p0 + i + 2;
        *(f4*)(vpad + (((size_t)b * 132 + (y + 2)) * 132 + xp) * 64 + c0) = acc[i];
    }
}

// ---------------------------------------------------------------------------
// Kernel E: conv3x3 + GELU via bf16 MFMA -> featb (bf16 NHWC)
// ---------------------------------------------------------------------------
__global__ __launch_bounds__(256, 4) void conv_mfma_k(const char* __restrict__ x2tp,
                                                      const char* __restrict__ wbfT,
                                                      const float* __restrict__ bc,
                                                      char* __restrict__ featb) {
    __shared__ char slab[3 * 8448];
    int tid = threadIdx.x;
    int l = tid & 63, w = tid >> 6;
    int bidx = blockIdx.x;
    int xb = bidx & 1, y = (bidx >> 1) & 127, b = bidx >> 8;
    int x0 = xb << 6;

    const char* gr = x2tp + ((size_t)(b * 130 + y) * 130 + x0) * 128;
    for (int q = w; q < 27; q += 4) {
        int r = q / 9, cq = q - r * 9;
        int nb = (cq < 8) ? 1024 : 256;
        if (l * 16 < nb) {
            const char* g = gr + (size_t)r * (130 * 128) + cq * 1024 + l * 16;
            char* p = slab + r * 8448 + cq * 1024 + l * 16;
            __builtin_amdgcn_global_load_lds(
                (const __attribute__((address_space(1))) u32*)g,
                (__attribute__((address_space(3))) u32*)p, 16, 0, 0);
        }
    }
    __syncthreads();

    int m0 = w << 4;
    int r16 = l & 15, g16 = l >> 4;
    f32x4 acc[4] = {{0.f,0.f,0.f,0.f},{0.f,0.f,0.f,0.f},
                    {0.f,0.f,0.f,0.f},{0.f,0.f,0.f,0.f}};
    const char* wb = wbfT + (size_t)r16 * 1152 + g16 * 16;

    #pragma unroll
    for (int s = 0; s < 18; s++) {
        const int t9 = s >> 1;
        const int ky = t9 / 3, kx = t9 - ky * 3;
        const int ci0g = (s & 1) * 4;
        int x_sl = m0 + r16 + kx;
        int go = (ci0g + g16) ^ (x_sl & 7);
        short8 a = *(const short8*)(slab + ky * 8448 + x_sl * 128 + go * 16);
        #pragma unroll
        for (int cb = 0; cb < 4; cb++) {
            short8 bf = *(const short8*)(wb + (size_t)cb * (16 * 1152) + s * 64);
            acc[cb] = __builtin_amdgcn_mfma_f32_16x16x32_bf16(a, bf, acc[cb], 0, 0, 0);
        }
    }

    const float kA = 0.7978845608028654f, kB = 0.044715f;
    char* fp = featb + ((size_t)b * 16384 + (size_t)y * 128 + x0 + m0) * 128;
    #pragma unroll
    for (int cb = 0; cb < 4; cb++) {
        float bcv = bc[cb * 16 + r16];
        #pragma unroll
        for (int j = 0; j < 4; j++) {
            float v = acc[cb][j] + bcv;
            float z = kA * (v + kB * v * v * v);
            float e = __expf(2.f * z);
            float th = 1.f - 2.f / (e + 1.f);
            float o = 0.5f * v * (1.f + th);
            *(u16*)(fp + (size_t)(g16 * 4 + j) * 128 + (cb * 16 + r16) * 2) = f2bf(o);
        }
    }
}

// ---------------------------------------------------------------------------
// Kernel F (v3): heads via bf16 MFMA + lane-parallel softmax + px-parallel
// f4-vector sampling (2-ring zero pad, branch-free) + fp32 out proj.
// Block = 256 thr = 4 waves; wave owns 16 px; ALL LDS wave-private, 0 barriers.
// ---------------------------------------------------------------------------
__global__ __launch_bounds__(256, 3) void dcn_fused_v3(const char* __restrict__ featb,
                                                       const float* __restrict__ vpad,
                                                       const char* __restrict__ whead,
                                                       const float* __restrict__ bo,
                                                       const float* __restrict__ bm,
                                                       const float* __restrict__ wout,
                                                       const float* __restrict__ bout,
                                                       float* __restrict__ out) {
    __shared__ float off_s [4][16][74];
    __shared__ float msk_s [4][16][38];
    __shared__ float samp_s[4][16][64];

    int tid = threadIdx.x;
    int w = tid >> 6, l = tid & 63;
    int blk = blockIdx.x;                 // 1024 blocks: b(4) x y(128) x xh(2)
    int b = blk >> 8, y = (blk >> 1) & 127, xh = blk & 1;
    int x0w = xh * 64 + w * 16;
    int pix0 = ((b << 7) + y) * 128 + x0w;

    int r = l & 15, q = l >> 4;

    // ---- A-frags from bf16 feat: row = px = r, k-chunk = q
    const char* fpt = featb + (size_t)(pix0 + r) * 128 + q * 16;
    short8 a0 = *(const short8*)fpt;
    short8 a1 = *(const short8*)(fpt + 64);

    // ---- head GEMM: 7 col-tiles x 2 k-steps
    const char* wh = whead + (size_t)r * 128 + q * 16;
    f32x4 hc[7];
    #pragma unroll
    for (int t = 0; t < 7; t++) {
        short8 b0 = *(const short8*)(wh + t * 2048);
        short8 b1 = *(const short8*)(wh + t * 2048 + 64);
        f32x4 z = {0.f, 0.f, 0.f, 0.f};
        z = __builtin_amdgcn_mfma_f32_16x16x32_bf16(a0, b0, z, 0, 0, 0);
        hc[t] = __builtin_amdgcn_mfma_f32_16x16x32_bf16(a1, b1, z, 0, 0, 0);
    }

    // ---- C scatter to LDS (+bias): col = t*16+r, row/px = q*4+j
    #pragma unroll
    for (int t = 0; t < 7; t++) {
        int col = t * 16 + r;
        float bias = 0.f;
        if (col < 72)        bias = bo[col];
        else if (col < 108)  bias = bm[col - 72];
        #pragma unroll
        for (int j = 0; j < 4; j++) {
            int px = q * 4 + j;
            float v = hc[t][j] + bias;
            if (col < 72)       off_s[w][px][col] = v;
            else if (col < 108) msk_s[w][px][col - 72] = v;
        }
    }

    // ---- softmax: lane -> (px = l&15, g = l>>4), fully parallel
    {
        int px = r, g = q;
        float m[9];
        #pragma unroll
        for (int p = 0; p < 9; p++) m[p] = msk_s[w][px][g * 9 + p];
        float mx = m[0];
        #pragma unroll
        for (int p = 1; p < 9; p++) mx = fmaxf(mx, m[p]);
        float s = 0.f;
        #pragma unroll
        for (int p = 0; p < 9; p++) { m[p] = __expf(m[p] - mx); s += m[p]; }
        float inv = 1.f / s;
        #pragma unroll
        for (int p = 0; p < 9; p++) msk_s[w][px][g * 9 + p] = m[p] * inv;
    }

    // ---- sampling: lane = (cc4 = l&3, g = (l>>2)&3, pxs = l>>4); 4 px / lane
    {
        int cc4 = l & 3, g = (l >> 2) & 3, pxs = l >> 4;
        const float* vb = vpad + (size_t)b * 17424 * 64 + g * 16 + cc4 * 4;
        #pragma unroll
        for (int j = 0; j < 4; j++) {
            int px = pxs * 4 + j;
            int xpix = x0w + px;
            f4 acc = {0.f, 0.f, 0.f, 0.f};
            #pragma unroll
            for (int p = 0; p < 9; p++) {
                const int kx = p % 3, ky = p / 3;
                f2 oxy = *(const f2*)&off_s[w][px][g * 18 + 2 * p];
                float mv = msk_s[w][px][g * 9 + p];
                float sx = (float)(xpix + kx) + oxy[0];   // 1-pad coords
                float sy = (float)(y + ky) + oxy[1];
                float xf = floorf(sx), yf = floorf(sy);
                float fx = sx - xf, fy = sy - yf;
                int ix = (int)xf, iy = (int)yf;           // in [-1,129]
                int e0 = (iy * 132 + ix + 133) << 6;      // elem offset in 2-pad map
                const float* pa = vb + e0;
                f4 v00 = *(const f4*)pa;
                f4 v01 = *(const f4*)(pa + 64);
                f4 v10 = *(const f4*)(pa + 8448);
                f4 v11 = *(const f4*)(pa + 8512);
                float wy0 = mv * (1.f - fy), wy1 = mv * fy;
                float w00 = wy0 * (1.f - fx), w01 = wy0 * fx;
                float w10 = wy1 * (1.f - fx), w11 = wy1 * fx;
                #pragma unroll
                for (int c = 0; c < 4; c++)
                    acc[c] = fmaf(w00, v00[c],
                             fmaf(w01, v01[c],
                             fmaf(w10, v10[c],
                             fmaf(w11, v11[c], acc[c]))));
            }
            *(f4*)&samp_s[w][px][g * 16 + cc4 * 4] = acc;
        }
    }

    // ---- out projection (fp32): lane = out-ch, 16 px batched
    float oa[16];
    float bv = bout[l];
    #pragma unroll
    for (int px = 0; px < 16; px++) oa[px] = bv;
    const float* pw = wout + l;
    #pragma unroll 4
    for (int k4 = 0; k4 < 16; k4++) {
        float w0 = pw[0], w1 = pw[64], w2 = pw[128], w3 = pw[192];
        pw += 256;
        #pragma unroll
        for (int px = 0; px < 16; px++) {
            f4 sv = *(f4*)&samp_s[w][px][k4 * 4];
            oa[px] = fmaf(sv[0], w0, fmaf(sv[1], w1,
                     fmaf(sv[2], w2, fmaf(sv[3], w3, oa[px]))));
        }
    }

    // ---- NCHW store: lane = channel, 16 consecutive x
    float* op = out + ((size_t)b * 64 + l) * 16384 + y * 128 + x0w;
    f4 o0 = {oa[0],  oa[1],  oa[2],  oa[3]};
    f4 o1 = {oa[4],  oa[5],  oa[6],  oa[7]};
    f4 o2 = {oa[8],  oa[9],  oa[10], oa[11]};
    f4 o3 = {oa[12], oa[13], oa[14], oa[15]};
    *(f4*)op        = o0;
    *(f4*)(op + 4)  = o1;
    *(f4*)(op + 8)  = o2;
    *(f4*)(op + 12) = o3;
}

// ---------------------------------------------------------------------------
extern "C" void kernel_launch(void* const* d_in, const int* in_sizes, int n_in,
                              void* d_out, int out_size, void* d_ws, size_t ws_size,
                              hipStream_t stream) {
    const float* x1       = (const float*)d_in[0];
    const float* x2       = (const float*)d_in[1];
    const float* w_value  = (const float*)d_in[2];
    const float* b_value  = (const float*)d_in[3];
    const float* w_conv   = (const float*)d_in[4];
    const float* b_conv   = (const float*)d_in[5];
    const float* w_offset = (const float*)d_in[6];
    const float* b_offset = (const float*)d_in[7];
    const float* w_mask   = (const float*)d_in[8];
    const float* b_mask   = (const float*)d_in[9];
    const float* w_out    = (const float*)d_in[10];
    const float* b_out    = (const float*)d_in[11];

    float* vpad  = (float*)d_ws;
    char*  featb = (char*)d_ws + 17842176;
    char*  x2tp  = (char*)d_ws + 26230784;
    char*  wbfT  = (char*)d_ws + 34883584;
    char*  whead = (char*)d_ws + 34957312;
    float* outp  = (float*)d_out;

    hipLaunchKernelGGL(prep_zero_k,  dim3(325),  dim3(256), 0, stream, vpad, x2tp);
    hipLaunchKernelGGL(prep_w_k,     dim3(100),  dim3(256), 0, stream,
                       w_conv, w_offset, w_mask, wbfT, whead);
    hipLaunchKernelGGL(x2prep_k,     dim3(512),  dim3(256), 0, stream, x2, x2tp);
    hipLaunchKernelGGL(value_proj_k, dim3(1024), dim3(256), 0, stream,
                       x1, w_value, b_value, vpad);
    hipLaunchKernelGGL(conv_mfma_k,  dim3(1024), dim3(256), 0, stream,
                       x2tp, wbfT, b_conv, featb);
    hipLaunchKernelGGL(dcn_fused_v3, dim3(1024), dim3(256), 0, stream,
                       featb, vpad, whead, b_offset, b_mask, w_out, b_out, outp);
}

// Round 6
// 216.787 us; speedup vs baseline: 1.5476x; 1.0390x over previous
//
#include <hip/hip_runtime.h>
#include <cstdint>
#include <cstddef>

typedef float f4 __attribute__((ext_vector_type(4)));
typedef float f2 __attribute__((ext_vector_type(2)));
typedef float f32x4 __attribute__((ext_vector_type(4)));
typedef short short8 __attribute__((ext_vector_type(8)));
typedef unsigned int u32;
typedef unsigned short u16;
typedef u32 u32x4 __attribute__((ext_vector_type(4)));

// Problem: B=4, H=W=128, CH=64 (G=4 x GC=16), K=3, PAD=1, P=9
// ws layout:
//   vpad  fp32 [4][132][132][64] (2-ring zero) @ 0          17,842,176 B
//   featb bf16 [4][16384][64]                  @ 17,842,176  8,388,608 B
//   x2tp  bf16 [4][130][130][64] swizzled      @ 26,230,784  8,652,800 B
//   wbfT  bf16 [64][576]                       @ 34,883,584     73,728 B
//   whead bf16 [112 cols][64 k]                @ 34,957,312     14,336 B
//
// XCD swizzle (T1): the three 1024-block heavy kernels remap
// blk' = (d%8)*128 + d/8 so each XCD owns a contiguous (b, y-band) chunk;
// keeps the bilinear-gather window (~1.7 MB/XCD) L2-resident instead of
// thrashing (v3: ~13 MB/XCD -> 99 MB L2-miss fetch).

__device__ __forceinline__ u16 f2bf(float f) {
    u32 u = __builtin_bit_cast(u32, f);
    return (u16)((u + 0x7FFFu + ((u >> 16) & 1u)) >> 16);
}

__device__ __forceinline__ int xcd_swz(int d) {
    return ((d & 7) << 7) | (d >> 3);      // 1024 blocks, 8 XCDs, 128-chunks
}

// ---------------------------------------------------------------------------
// Kernel A: zero 2-px ring of vpad + 1-px ring of x2tp (ws poisoned each call)
// ---------------------------------------------------------------------------
__global__ __launch_bounds__(256) void prep_zero_k(float* __restrict__ vpad,
                                                   char* __restrict__ x2tp) {
    int blk = blockIdx.x;
    if (blk < 260) {
        int i = blk * 256 + threadIdx.x;
        if (i >= 66560) return;
        int c4 = i & 15;
        int rest = i >> 4;
        int b = rest / 1040;
        int e = rest - b * 1040;
        int y, x;
        if (e < 132)      { y = 0;   x = e; }
        else if (e < 264) { y = 1;   x = e - 132; }
        else if (e < 396) { y = 130; x = e - 264; }
        else if (e < 528) { y = 131; x = e - 396; }
        else { int e2 = e - 528; y = 2 + (e2 >> 2); int m = e2 & 3;
               x = (m < 2) ? m : m + 128; }
        f4 z = {0.f, 0.f, 0.f, 0.f};
        *(f4*)(vpad + (((size_t)b * 17424 + (size_t)y * 132 + x) * 64 + c4 * 4)) = z;
    } else {
        int i = (blk - 260) * 256 + threadIdx.x;
        if (i >= 16512) return;
        int c8 = i & 7;
        int rest = i >> 3;
        int b = rest / 516;
        int e = rest - b * 516;
        int y, x;
        if (e < 130)      { y = 0;       x = e; }
        else if (e < 260) { y = 129;     x = e - 130; }
        else if (e < 388) { y = e - 259; x = 0; }
        else              { y = e - 387; x = 129; }
        u32x4 z = {0u, 0u, 0u, 0u};
        *(u32x4*)(x2tp + ((size_t)b * 16900 + (size_t)y * 130 + x) * 128 + c8 * 16) = z;
    }
}

// ---------------------------------------------------------------------------
// Kernel B: weight prep (w_conv -> wbfT; wo||wm -> whead)
// ---------------------------------------------------------------------------
__global__ __launch_bounds__(256) void prep_w_k(const float* __restrict__ wc,
                                                const float* __restrict__ wo,
                                                const float* __restrict__ wm,
                                                char* __restrict__ wbfT,
                                                char* __restrict__ whead) {
    int blk = blockIdx.x;
    if (blk < 72) {
        int i = blk * 256 + threadIdx.x;
        int c = i / 288, kp = i - c * 288;
        int k = kp << 1;
        float f0 = wc[(size_t)k * 64 + c];
        float f1 = wc[(size_t)(k + 1) * 64 + c];
        u32 pk = (u32)f2bf(f0) | ((u32)f2bf(f1) << 16);
        *(u32*)(wbfT + (size_t)c * 1152 + kp * 4) = pk;
    } else {
        int i = (blk - 72) * 256 + threadIdx.x;
        int k = i & 63, col = i >> 6;
        float v = 0.f;
        if (col < 72)       v = wo[(size_t)k * 72 + col];
        else if (col < 108) v = wm[(size_t)k * 36 + col - 72];
        *(u16*)(whead + (size_t)(col * 64 + k) * 2) = f2bf(v);
    }
}

// ---------------------------------------------------------------------------
// Kernel C: x2 NCHW fp32 -> x2tp padded NHWC bf16, octet-XOR-swizzled.
// ---------------------------------------------------------------------------
__global__ __launch_bounds__(256) void x2prep_k(const float* __restrict__ x2,
                                                char* __restrict__ x2tp) {
    __shared__ u32 tr[4096];
    int t = threadIdx.x;
    int y = blockIdx.x & 127, b = blockIdx.x >> 7;
    const float* xb = x2 + (size_t)b * 64 * 16384 + (size_t)y * 128;
    #pragma unroll 4
    for (int j = 0; j < 16; j++) {
        int idx = t + (j << 8);
        int x = idx & 127, cip = idx >> 7;
        int ci = cip << 1;
        float f0 = xb[(size_t)ci * 16384 + x];
        float f1 = xb[(size_t)(ci + 1) * 16384 + x];
        u32 pk = (u32)f2bf(f0) | ((u32)f2bf(f1) << 16);
        int key = (x + 1) & 7;
        int byt = x * 128 + (((ci >> 3) ^ key) << 4) + (ci & 7) * 2;
        tr[byt >> 2] = pk;
    }
    __syncthreads();
    const u32x4* src = (const u32x4*)tr;
    u32x4* dst = (u32x4*)(x2tp + ((size_t)(b * 130 + y + 1) * 130 + 1) * 128);
    #pragma unroll
    for (int j = 0; j < 4; j++) {
        int c = t + (j << 8);
        dst[c] = src[c];
    }
}

// ---------------------------------------------------------------------------
// Kernel D: value = x1(NCHW) @ w_value + b_value -> vpad interior (fp32)
// ---------------------------------------------------------------------------
__global__ __launch_bounds__(256) void value_proj_k(const float* __restrict__ x1,
                                                    const float* __restrict__ wv,
                                                    const float* __restrict__ bv,
                                                    float* __restrict__ vpad) {
    __shared__ float xs[64][64];
    __shared__ float wsh[64][64];
    int tid = threadIdx.x;
    int bidx = xcd_swz(blockIdx.x);
    int xb = bidx & 1;
    int y  = (bidx >> 1) & 127;
    int b  = bidx >> 8;
    int x0 = xb * 64;

    for (int j = 0; j < 16; j++) {
        int idx = tid + j * 256;
        int ci = idx >> 6, px = idx & 63;
        xs[ci][px]  = x1[(((size_t)b * 64 + ci) * 128 + y) * 128 + x0 + px];
        wsh[ci][px] = wv[idx];
    }
    __syncthreads();

    int c0 = (tid & 15) * 4, p0 = (tid >> 4) * 4;
    f4 bb = *(const f4*)(bv + c0);
    f4 acc[4];
    #pragma unroll
    for (int i = 0; i < 4; i++) acc[i] = bb;

    #pragma unroll
    for (int ci = 0; ci < 64; ci++) {
        f4 w4 = *(f4*)&wsh[ci][c0];
        f4 x4 = *(f4*)&xs[ci][p0];
        #pragma unroll
        for (int i = 0; i < 4; i++) acc[i] += x4[i] * w4;
    }

    #pragma unroll
    for (int i = 0; i < 4; i++) {
        int xp = x0 + p0 + i + 2;
        *(f4*)(vpad + (((size_t)b * 132 + (y + 2)) * 132 + xp) * 64 + c0) = acc[i];
    }
}

// ---------------------------------------------------------------------------
// Kernel E: conv3x3 + GELU via bf16 MFMA -> featb (bf16 NHWC)
// ---------------------------------------------------------------------------
__global__ __launch_bounds__(256, 4) void conv_mfma_k(const char* __restrict__ x2tp,
                                                      const char* __restrict__ wbfT,
                                                      const float* __restrict__ bc,
                                                      char* __restrict__ featb) {
    __shared__ char slab[3 * 8448];
    int tid = threadIdx.x;
    int l = tid & 63, w = tid >> 6;
    int bidx = xcd_swz(blockIdx.x);
    int xb = bidx & 1, y = (bidx >> 1) & 127, b = bidx >> 8;
    int x0 = xb << 6;

    const char* gr = x2tp + ((size_t)(b * 130 + y) * 130 + x0) * 128;
    for (int q = w; q < 27; q += 4) {
        int r = q / 9, cq = q - r * 9;
        int nb = (cq < 8) ? 1024 : 256;
        if (l * 16 < nb) {
            const char* g = gr + (size_t)r * (130 * 128) + cq * 1024 + l * 16;
            char* p = slab + r * 8448 + cq * 1024 + l * 16;
            __builtin_amdgcn_global_load_lds(
                (const __attribute__((address_space(1))) u32*)g,
                (__attribute__((address_space(3))) u32*)p, 16, 0, 0);
        }
    }
    __syncthreads();

    int m0 = w << 4;
    int r16 = l & 15, g16 = l >> 4;
    f32x4 acc[4] = {{0.f,0.f,0.f,0.f},{0.f,0.f,0.f,0.f},
                    {0.f,0.f,0.f,0.f},{0.f,0.f,0.f,0.f}};
    const char* wb = wbfT + (size_t)r16 * 1152 + g16 * 16;

    #pragma unroll
    for (int s = 0; s < 18; s++) {
        const int t9 = s >> 1;
        const int ky = t9 / 3, kx = t9 - ky * 3;
        const int ci0g = (s & 1) * 4;
        int x_sl = m0 + r16 + kx;
        int go = (ci0g + g16) ^ (x_sl & 7);
        short8 a = *(const short8*)(slab + ky * 8448 + x_sl * 128 + go * 16);
        #pragma unroll
        for (int cb = 0; cb < 4; cb++) {
            short8 bf = *(const short8*)(wb + (size_t)cb * (16 * 1152) + s * 64);
            acc[cb] = __builtin_amdgcn_mfma_f32_16x16x32_bf16(a, bf, acc[cb], 0, 0, 0);
        }
    }

    const float kA = 0.7978845608028654f, kB = 0.044715f;
    char* fp = featb + ((size_t)b * 16384 + (size_t)y * 128 + x0 + m0) * 128;
    #pragma unroll
    for (int cb = 0; cb < 4; cb++) {
        float bcv = bc[cb * 16 + r16];
        #pragma unroll
        for (int j = 0; j < 4; j++) {
            float v = acc[cb][j] + bcv;
            float z = kA * (v + kB * v * v * v);
            float e = __expf(2.f * z);
            float th = 1.f - 2.f / (e + 1.f);
            float o = 0.5f * v * (1.f + th);
            *(u16*)(fp + (size_t)(g16 * 4 + j) * 128 + (cb * 16 + r16) * 2) = f2bf(o);
        }
    }
}

// ---------------------------------------------------------------------------
// Kernel F (v4): = v3 + XCD-chunked scheduling. Heads via bf16 MFMA,
// lane-parallel softmax, px-parallel f4 sampling, fp32 out proj. 0 barriers.
// ---------------------------------------------------------------------------
__global__ __launch_bounds__(256, 3) void dcn_fused_v4(const char* __restrict__ featb,
                                                       const float* __restrict__ vpad,
                                                       const char* __restrict__ whead,
                                                       const float* __restrict__ bo,
                                                       const float* __restrict__ bm,
                                                       const float* __restrict__ wout,
                                                       const float* __restrict__ bout,
                                                       float* __restrict__ out) {
    __shared__ float off_s [4][16][74];
    __shared__ float msk_s [4][16][38];
    __shared__ float samp_s[4][16][64];

    int tid = threadIdx.x;
    int w = tid >> 6, l = tid & 63;
    int blk = xcd_swz(blockIdx.x);        // b(4) x y(128) x xh(2), chunked/XCD
    int b = blk >> 8, y = (blk >> 1) & 127, xh = blk & 1;
    int x0w = xh * 64 + w * 16;
    int pix0 = ((b << 7) + y) * 128 + x0w;

    int r = l & 15, q = l >> 4;

    // ---- A-frags from bf16 feat
    const char* fpt = featb + (size_t)(pix0 + r) * 128 + q * 16;
    short8 a0 = *(const short8*)fpt;
    short8 a1 = *(const short8*)(fpt + 64);

    // ---- head GEMM: 7 col-tiles x 2 k-steps
    const char* wh = whead + (size_t)r * 128 + q * 16;
    f32x4 hc[7];
    #pragma unroll
    for (int t = 0; t < 7; t++) {
        short8 b0 = *(const short8*)(wh + t * 2048);
        short8 b1 = *(const short8*)(wh + t * 2048 + 64);
        f32x4 z = {0.f, 0.f, 0.f, 0.f};
        z = __builtin_amdgcn_mfma_f32_16x16x32_bf16(a0, b0, z, 0, 0, 0);
        hc[t] = __builtin_amdgcn_mfma_f32_16x16x32_bf16(a1, b1, z, 0, 0, 0);
    }

    // ---- C scatter to LDS (+bias)
    #pragma unroll
    for (int t = 0; t < 7; t++) {
        int col = t * 16 + r;
        float bias = 0.f;
        if (col < 72)        bias = bo[col];
        else if (col < 108)  bias = bm[col - 72];
        #pragma unroll
        for (int j = 0; j < 4; j++) {
            int px = q * 4 + j;
            float v = hc[t][j] + bias;
            if (col < 72)       off_s[w][px][col] = v;
            else if (col < 108) msk_s[w][px][col - 72] = v;
        }
    }

    // ---- softmax: lane -> (px = l&15, g = l>>4), fully parallel
    {
        int px = r, g = q;
        float m[9];
        #pragma unroll
        for (int p = 0; p < 9; p++) m[p] = msk_s[w][px][g * 9 + p];
        float mx = m[0];
        #pragma unroll
        for (int p = 1; p < 9; p++) mx = fmaxf(mx, m[p]);
        float s = 0.f;
        #pragma unroll
        for (int p = 0; p < 9; p++) { m[p] = __expf(m[p] - mx); s += m[p]; }
        float inv = 1.f / s;
        #pragma unroll
        for (int p = 0; p < 9; p++) msk_s[w][px][g * 9 + p] = m[p] * inv;
    }

    // ---- sampling: lane = (cc4 = l&3, g = (l>>2)&3, pxs = l>>4); 4 px / lane
    {
        int cc4 = l & 3, g = (l >> 2) & 3, pxs = l >> 4;
        const float* vb = vpad + (size_t)b * 17424 * 64 + g * 16 + cc4 * 4;
        #pragma unroll
        for (int j = 0; j < 4; j++) {
            int px = pxs * 4 + j;
            int xpix = x0w + px;
            f4 acc = {0.f, 0.f, 0.f, 0.f};
            #pragma unroll
            for (int p = 0; p < 9; p++) {
                const int kx = p % 3, ky = p / 3;
                f2 oxy = *(const f2*)&off_s[w][px][g * 18 + 2 * p];
                float mv = msk_s[w][px][g * 9 + p];
                float sx = (float)(xpix + kx) + oxy[0];
                float sy = (float)(y + ky) + oxy[1];
                float xf = floorf(sx), yf = floorf(sy);
                float fx = sx - xf, fy = sy - yf;
                int ix = (int)xf, iy = (int)yf;           // in [-1,129]
                int e0 = (iy * 132 + ix + 133) << 6;
                const float* pa = vb + e0;
                f4 v00 = *(const f4*)pa;
                f4 v01 = *(const f4*)(pa + 64);
                f4 v10 = *(const f4*)(pa + 8448);
                f4 v11 = *(const f4*)(pa + 8512);
                float wy0 = mv * (1.f - fy), wy1 = mv * fy;
                float w00 = wy0 * (1.f - fx), w01 = wy0 * fx;
                float w10 = wy1 * (1.f - fx), w11 = wy1 * fx;
                #pragma unroll
                for (int c = 0; c < 4; c++)
                    acc[c] = fmaf(w00, v00[c],
                             fmaf(w01, v01[c],
                             fmaf(w10, v10[c],
                             fmaf(w11, v11[c], acc[c]))));
            }
            *(f4*)&samp_s[w][px][g * 16 + cc4 * 4] = acc;
        }
    }

    // ---- out projection (fp32): lane = out-ch, 16 px batched
    float oa[16];
    float bv = bout[l];
    #pragma unroll
    for (int px = 0; px < 16; px++) oa[px] = bv;
    const float* pw = wout + l;
    #pragma unroll 4
    for (int k4 = 0; k4 < 16; k4++) {
        float w0 = pw[0], w1 = pw[64], w2 = pw[128], w3 = pw[192];
        pw += 256;
        #pragma unroll
        for (int px = 0; px < 16; px++) {
            f4 sv = *(f4*)&samp_s[w][px][k4 * 4];
            oa[px] = fmaf(sv[0], w0, fmaf(sv[1], w1,
                     fmaf(sv[2], w2, fmaf(sv[3], w3, oa[px]))));
        }
    }

    // ---- NCHW store: lane = channel, 16 consecutive x (64 B/lane)
    float* op = out + ((size_t)b * 64 + l) * 16384 + y * 128 + x0w;
    f4 o0 = {oa[0],  oa[1],  oa[2],  oa[3]};
    f4 o1 = {oa[4],  oa[5],  oa[6],  oa[7]};
    f4 o2 = {oa[8],  oa[9],  oa[10], oa[11]};
    f4 o3 = {oa[12], oa[13], oa[14], oa[15]};
    *(f4*)op        = o0;
    *(f4*)(op + 4)  = o1;
    *(f4*)(op + 8)  = o2;
    *(f4*)(op + 12) = o3;
}

// ---------------------------------------------------------------------------
extern "C" void kernel_launch(void* const* d_in, const int* in_sizes, int n_in,
                              void* d_out, int out_size, void* d_ws, size_t ws_size,
                              hipStream_t stream) {
    const float* x1       = (const float*)d_in[0];
    const float* x2       = (const float*)d_in[1];
    const float* w_value  = (const float*)d_in[2];
    const float* b_value  = (const float*)d_in[3];
    const float* w_conv   = (const float*)d_in[4];
    const float* b_conv   = (const float*)d_in[5];
    const float* w_offset = (const float*)d_in[6];
    const float* b_offset = (const float*)d_in[7];
    const float* w_mask   = (const float*)d_in[8];
    const float* b_mask   = (const float*)d_in[9];
    const float* w_out    = (const float*)d_in[10];
    const float* b_out    = (const float*)d_in[11];

    float* vpad  = (float*)d_ws;
    char*  featb = (char*)d_ws + 17842176;
    char*  x2tp  = (char*)d_ws + 26230784;
    char*  wbfT  = (char*)d_ws + 34883584;
    char*  whead = (char*)d_ws + 34957312;
    float* outp  = (float*)d_out;

    hipLaunchKernelGGL(prep_zero_k,  dim3(325),  dim3(256), 0, stream, vpad, x2tp);
    hipLaunchKernelGGL(prep_w_k,     dim3(100),  dim3(256), 0, stream,
                       w_conv, w_offset, w_mask, wbfT, whead);
    hipLaunchKernelGGL(x2prep_k,     dim3(512),  dim3(256), 0, stream, x2, x2tp);
    hipLaunchKernelGGL(value_proj_k, dim3(1024), dim3(256), 0, stream,
                       x1, w_value, b_value, vpad);
    hipLaunchKernelGGL(conv_mfma_k,  dim3(1024), dim3(256), 0, stream,
                       x2tp, wbfT, b_conv, featb);
    hipLaunchKernelGGL(dcn_fused_v4, dim3(1024), dim3(256), 0, stream,
                       featb, vpad, whead, b_offset, b_mask, w_out, b_out, outp);
}

// Round 7
// 198.921 us; speedup vs baseline: 1.6866x; 1.0898x over previous
//
#include <hip/hip_runtime.h>
#include <cstdint>
#include <cstddef>

typedef float f4 __attribute__((ext_vector_type(4)));
typedef float f2 __attribute__((ext_vector_type(2)));
typedef float f32x4 __attribute__((ext_vector_type(4)));
typedef short short8 __attribute__((ext_vector_type(8)));
typedef unsigned int u32;
typedef unsigned short u16;
typedef u32 u32x4 __attribute__((ext_vector_type(4)));

// Problem: B=4, H=W=128, CH=64 (G=4 x GC=16), K=3, PAD=1, P=9
// ws layout:
//   vpad  fp32 [4][132][132][64] (2-ring zero) @ 0          17,842,176 B
//   featb bf16 [4][16384][64]                  @ 17,842,176  8,388,608 B
//   x2tp  bf16 [4][130][130][64] swizzled      @ 26,230,784  8,652,800 B
//   wbfT  bf16 [64][576]                       @ 34,883,584     73,728 B
//   whead bf16 [112 cols][64 k]                @ 34,957,312     14,336 B

__device__ __forceinline__ u16 f2bf(float f) {
    u32 u = __builtin_bit_cast(u32, f);
    return (u16)((u + 0x7FFFu + ((u >> 16) & 1u)) >> 16);
}

__device__ __forceinline__ int xcd_swz10(int d) {   // 1024 blocks
    return ((d & 7) << 7) | (d >> 3);
}
__device__ __forceinline__ int xcd_swz11(int d) {   // 2048 blocks
    return ((d & 7) << 8) | (d >> 3);
}

// ---------------------------------------------------------------------------
// Kernel A: zero 2-px ring of vpad + 1-px ring of x2tp (ws poisoned each call)
// ---------------------------------------------------------------------------
__global__ __launch_bounds__(256) void prep_zero_k(float* __restrict__ vpad,
                                                   char* __restrict__ x2tp) {
    int blk = blockIdx.x;
    if (blk < 260) {
        int i = blk * 256 + threadIdx.x;
        if (i >= 66560) return;
        int c4 = i & 15;
        int rest = i >> 4;
        int b = rest / 1040;
        int e = rest - b * 1040;
        int y, x;
        if (e < 132)      { y = 0;   x = e; }
        else if (e < 264) { y = 1;   x = e - 132; }
        else if (e < 396) { y = 130; x = e - 264; }
        else if (e < 528) { y = 131; x = e - 396; }
        else { int e2 = e - 528; y = 2 + (e2 >> 2); int m = e2 & 3;
               x = (m < 2) ? m : m + 128; }
        f4 z = {0.f, 0.f, 0.f, 0.f};
        *(f4*)(vpad + (((size_t)b * 17424 + (size_t)y * 132 + x) * 64 + c4 * 4)) = z;
    } else {
        int i = (blk - 260) * 256 + threadIdx.x;
        if (i >= 16512) return;
        int c8 = i & 7;
        int rest = i >> 3;
        int b = rest / 516;
        int e = rest - b * 516;
        int y, x;
        if (e < 130)      { y = 0;       x = e; }
        else if (e < 260) { y = 129;     x = e - 130; }
        else if (e < 388) { y = e - 259; x = 0; }
        else              { y = e - 387; x = 129; }
        u32x4 z = {0u, 0u, 0u, 0u};
        *(u32x4*)(x2tp + ((size_t)b * 16900 + (size_t)y * 130 + x) * 128 + c8 * 16) = z;
    }
}

// ---------------------------------------------------------------------------
// Kernel B: weight prep (w_conv -> wbfT; wo||wm -> whead)
// ---------------------------------------------------------------------------
__global__ __launch_bounds__(256) void prep_w_k(const float* __restrict__ wc,
                                                const float* __restrict__ wo,
                                                const float* __restrict__ wm,
                                                char* __restrict__ wbfT,
                                                char* __restrict__ whead) {
    int blk = blockIdx.x;
    if (blk < 72) {
        int i = blk * 256 + threadIdx.x;
        int c = i / 288, kp = i - c * 288;
        int k = kp << 1;
        float f0 = wc[(size_t)k * 64 + c];
        float f1 = wc[(size_t)(k + 1) * 64 + c];
        u32 pk = (u32)f2bf(f0) | ((u32)f2bf(f1) << 16);
        *(u32*)(wbfT + (size_t)c * 1152 + kp * 4) = pk;
    } else {
        int i = (blk - 72) * 256 + threadIdx.x;
        int k = i & 63, col = i >> 6;
        float v = 0.f;
        if (col < 72)       v = wo[(size_t)k * 72 + col];
        else if (col < 108) v = wm[(size_t)k * 36 + col - 72];
        *(u16*)(whead + (size_t)(col * 64 + k) * 2) = f2bf(v);
    }
}

// ---------------------------------------------------------------------------
// Kernel C: x2 NCHW fp32 -> x2tp padded NHWC bf16, octet-XOR-swizzled.
// ---------------------------------------------------------------------------
__global__ __launch_bounds__(256) void x2prep_k(const float* __restrict__ x2,
                                                char* __restrict__ x2tp) {
    __shared__ u32 tr[4096];
    int t = threadIdx.x;
    int y = blockIdx.x & 127, b = blockIdx.x >> 7;
    const float* xb = x2 + (size_t)b * 64 * 16384 + (size_t)y * 128;
    #pragma unroll 4
    for (int j = 0; j < 16; j++) {
        int idx = t + (j << 8);
        int x = idx & 127, cip = idx >> 7;
        int ci = cip << 1;
        float f0 = xb[(size_t)ci * 16384 + x];
        float f1 = xb[(size_t)(ci + 1) * 16384 + x];
        u32 pk = (u32)f2bf(f0) | ((u32)f2bf(f1) << 16);
        int key = (x + 1) & 7;
        int byt = x * 128 + (((ci >> 3) ^ key) << 4) + (ci & 7) * 2;
        tr[byt >> 2] = pk;
    }
    __syncthreads();
    const u32x4* src = (const u32x4*)tr;
    u32x4* dst = (u32x4*)(x2tp + ((size_t)(b * 130 + y + 1) * 130 + 1) * 128);
    #pragma unroll
    for (int j = 0; j < 4; j++) {
        int c = t + (j << 8);
        dst[c] = src[c];
    }
}

// ---------------------------------------------------------------------------
// Kernel D: value = x1(NCHW) @ w_value + b_value -> vpad interior (fp32)
// ---------------------------------------------------------------------------
__global__ __launch_bounds__(256) void value_proj_k(const float* __restrict__ x1,
                                                    const float* __restrict__ wv,
                                                    const float* __restrict__ bv,
                                                    float* __restrict__ vpad) {
    __shared__ float xs[64][64];
    __shared__ float wsh[64][64];
    int tid = threadIdx.x;
    int bidx = xcd_swz10(blockIdx.x);
    int xb = bidx & 1;
    int y  = (bidx >> 1) & 127;
    int b  = bidx >> 8;
    int x0 = xb * 64;

    for (int j = 0; j < 16; j++) {
        int idx = tid + j * 256;
        int ci = idx >> 6, px = idx & 63;
        xs[ci][px]  = x1[(((size_t)b * 64 + ci) * 128 + y) * 128 + x0 + px];
        wsh[ci][px] = wv[idx];
    }
    __syncthreads();

    int c0 = (tid & 15) * 4, p0 = (tid >> 4) * 4;
    f4 bb = *(const f4*)(bv + c0);
    f4 acc[4];
    #pragma unroll
    for (int i = 0; i < 4; i++) acc[i] = bb;

    #pragma unroll
    for (int ci = 0; ci < 64; ci++) {
        f4 w4 = *(f4*)&wsh[ci][c0];
        f4 x4 = *(f4*)&xs[ci][p0];
        #pragma unroll
        for (int i = 0; i < 4; i++) acc[i] += x4[i] * w4;
    }

    #pragma unroll
    for (int i = 0; i < 4; i++) {
        int xp = x0 + p0 + i + 2;
        *(f4*)(vpad + (((size_t)b * 132 + (y + 2)) * 132 + xp) * 64 + c0) = acc[i];
    }
}

// ---------------------------------------------------------------------------
// Kernel E: conv3x3 + GELU via bf16 MFMA -> featb (bf16 NHWC)
// ---------------------------------------------------------------------------
__global__ __launch_bounds__(256, 4) void conv_mfma_k(const char* __restrict__ x2tp,
                                                      const char* __restrict__ wbfT,
                                                      const float* __restrict__ bc,
                                                      char* __restrict__ featb) {
    __shared__ char slab[3 * 8448];
    int tid = threadIdx.x;
    int l = tid & 63, w = tid >> 6;
    int bidx = xcd_swz10(blockIdx.x);
    int xb = bidx & 1, y = (bidx >> 1) & 127, b = bidx >> 8;
    int x0 = xb << 6;

    const char* gr = x2tp + ((size_t)(b * 130 + y) * 130 + x0) * 128;
    for (int q = w; q < 27; q += 4) {
        int r = q / 9, cq = q - r * 9;
        int nb = (cq < 8) ? 1024 : 256;
        if (l * 16 < nb) {
            const char* g = gr + (size_t)r * (130 * 128) + cq * 1024 + l * 16;
            char* p = slab + r * 8448 + cq * 1024 + l * 16;
            __builtin_amdgcn_global_load_lds(
                (const __attribute__((address_space(1))) u32*)g,
                (__attribute__((address_space(3))) u32*)p, 16, 0, 0);
        }
    }
    __syncthreads();

    int m0 = w << 4;
    int r16 = l & 15, g16 = l >> 4;
    f32x4 acc[4] = {{0.f,0.f,0.f,0.f},{0.f,0.f,0.f,0.f},
                    {0.f,0.f,0.f,0.f},{0.f,0.f,0.f,0.f}};
    const char* wb = wbfT + (size_t)r16 * 1152 + g16 * 16;

    #pragma unroll
    for (int s = 0; s < 18; s++) {
        const int t9 = s >> 1;
        const int ky = t9 / 3, kx = t9 - ky * 3;
        const int ci0g = (s & 1) * 4;
        int x_sl = m0 + r16 + kx;
        int go = (ci0g + g16) ^ (x_sl & 7);
        short8 a = *(const short8*)(slab + ky * 8448 + x_sl * 128 + go * 16);
        #pragma unroll
        for (int cb = 0; cb < 4; cb++) {
            short8 bf = *(const short8*)(wb + (size_t)cb * (16 * 1152) + s * 64);
            acc[cb] = __builtin_amdgcn_mfma_f32_16x16x32_bf16(a, bf, acc[cb], 0, 0, 0);
        }
    }

    const float kA = 0.7978845608028654f, kB = 0.044715f;
    char* fp = featb + ((size_t)b * 16384 + (size_t)y * 128 + x0 + m0) * 128;
    #pragma unroll
    for (int cb = 0; cb < 4; cb++) {
        float bcv = bc[cb * 16 + r16];
        #pragma unroll
        for (int j = 0; j < 4; j++) {
            float v = acc[cb][j] + bcv;
            float z = kA * (v + kB * v * v * v);
            float e = __expf(2.f * z);
            float th = 1.f - 2.f / (e + 1.f);
            float o = 0.5f * v * (1.f + th);
            *(u16*)(fp + (size_t)(g16 * 4 + j) * 128 + (cb * 16 + r16) * 2) = f2bf(o);
        }
    }
}

// ---------------------------------------------------------------------------
// Kernel F (v5): v4 with 8 px/wave (2048 blocks) for 3x occupancy.
// LDS 22.5 KB/block; __launch_bounds__(256,6) -> ~24 waves/CU.
// MFMA head rows 8..15 are don't-cares (over-read into valid ws memory).
// ---------------------------------------------------------------------------
__global__ __launch_bounds__(256, 6) void dcn_fused_v5(const char* __restrict__ featb,
                                                       const float* __restrict__ vpad,
                                                       const char* __restrict__ whead,
                                                       const float* __restrict__ bo,
                                                       const float* __restrict__ bm,
                                                       const float* __restrict__ wout,
                                                       const float* __restrict__ bout,
                                                       float* __restrict__ out) {
    __shared__ float off_s [4][8][74];
    __shared__ float msk_s [4][8][38];
    __shared__ float samp_s[4][8][64];

    int tid = threadIdx.x;
    int w = tid >> 6, l = tid & 63;
    int blk = xcd_swz11(blockIdx.x);      // b(2) | y(7) | xq(2)
    int b = blk >> 9, y = (blk >> 2) & 127, xq = blk & 3;
    int x0w = xq * 32 + w * 8;
    int pix0 = ((b << 7) + y) * 128 + x0w;

    int r = l & 15, q = l >> 4;

    // ---- A-frags: 16 rows read, rows 8..15 discarded later (valid memory)
    const char* fpt = featb + (size_t)(pix0 + r) * 128 + q * 16;
    short8 a0 = *(const short8*)fpt;
    short8 a1 = *(const short8*)(fpt + 64);

    // ---- head GEMM: 7 col-tiles x 2 k-steps
    const char* wh = whead + (size_t)r * 128 + q * 16;
    f32x4 hc[7];
    #pragma unroll
    for (int t = 0; t < 7; t++) {
        short8 b0 = *(const short8*)(wh + t * 2048);
        short8 b1 = *(const short8*)(wh + t * 2048 + 64);
        f32x4 z = {0.f, 0.f, 0.f, 0.f};
        z = __builtin_amdgcn_mfma_f32_16x16x32_bf16(a0, b0, z, 0, 0, 0);
        hc[t] = __builtin_amdgcn_mfma_f32_16x16x32_bf16(a1, b1, z, 0, 0, 0);
    }

    // ---- C scatter to LDS (+bias): col = t*16+r, px = q*4+j (keep px<8)
    if (q < 2) {
        #pragma unroll
        for (int t = 0; t < 7; t++) {
            int col = t * 16 + r;
            float bias = 0.f;
            if (col < 72)        bias = bo[col];
            else if (col < 108)  bias = bm[col - 72];
            #pragma unroll
            for (int j = 0; j < 4; j++) {
                int px = q * 4 + j;
                float v = hc[t][j] + bias;
                if (col < 72)       off_s[w][px][col] = v;
                else if (col < 108) msk_s[w][px][col - 72] = v;
            }
        }
    }

    // ---- softmax: lanes 0..31 -> (px = l>>2, g = l&3), fully parallel
    if (l < 32) {
        int px = l >> 2, g = l & 3;
        float m[9];
        #pragma unroll
        for (int p = 0; p < 9; p++) m[p] = msk_s[w][px][g * 9 + p];
        float mx = m[0];
        #pragma unroll
        for (int p = 1; p < 9; p++) mx = fmaxf(mx, m[p]);
        float s = 0.f;
        #pragma unroll
        for (int p = 0; p < 9; p++) { m[p] = __expf(m[p] - mx); s += m[p]; }
        float inv = 1.f / s;
        #pragma unroll
        for (int p = 0; p < 9; p++) msk_s[w][px][g * 9 + p] = m[p] * inv;
    }

    // ---- sampling: lane = (cc4 = l&3, g = (l>>2)&3, pxs = l>>4); 2 px / lane
    {
        int cc4 = l & 3, g = (l >> 2) & 3, pxs = l >> 4;
        const float* vb = vpad + (size_t)b * 17424 * 64 + g * 16 + cc4 * 4;
        #pragma unroll
        for (int j = 0; j < 2; j++) {
            int px = pxs * 2 + j;
            int xpix = x0w + px;
            f4 acc = {0.f, 0.f, 0.f, 0.f};
            #pragma unroll
            for (int p = 0; p < 9; p++) {
                const int kx = p % 3, ky = p / 3;
                f2 oxy = *(const f2*)&off_s[w][px][g * 18 + 2 * p];
                float mv = msk_s[w][px][g * 9 + p];
                float sx = (float)(xpix + kx) + oxy[0];
                float sy = (float)(y + ky) + oxy[1];
                float xf = floorf(sx), yf = floorf(sy);
                float fx = sx - xf, fy = sy - yf;
                int ix = (int)xf, iy = (int)yf;           // in [-1,129]
                int e0 = (iy * 132 + ix + 133) << 6;
                const float* pa = vb + e0;
                f4 v00 = *(const f4*)pa;
                f4 v01 = *(const f4*)(pa + 64);
                f4 v10 = *(const f4*)(pa + 8448);
                f4 v11 = *(const f4*)(pa + 8512);
                float wy0 = mv * (1.f - fy), wy1 = mv * fy;
                float w00 = wy0 * (1.f - fx), w01 = wy0 * fx;
                float w10 = wy1 * (1.f - fx), w11 = wy1 * fx;
                #pragma unroll
                for (int c = 0; c < 4; c++)
                    acc[c] = fmaf(w00, v00[c],
                             fmaf(w01, v01[c],
                             fmaf(w10, v10[c],
                             fmaf(w11, v11[c], acc[c]))));
            }
            *(f4*)&samp_s[w][px][g * 16 + cc4 * 4] = acc;
        }
    }

    // ---- out projection (fp32): lane = out-ch, 8 px batched
    float oa[8];
    float bv = bout[l];
    #pragma unroll
    for (int px = 0; px < 8; px++) oa[px] = bv;
    const float* pw = wout + l;
    #pragma unroll 4
    for (int k4 = 0; k4 < 16; k4++) {
        float w0 = pw[0], w1 = pw[64], w2 = pw[128], w3 = pw[192];
        pw += 256;
        #pragma unroll
        for (int px = 0; px < 8; px++) {
            f4 sv = *(f4*)&samp_s[w][px][k4 * 4];
            oa[px] = fmaf(sv[0], w0, fmaf(sv[1], w1,
                     fmaf(sv[2], w2, fmaf(sv[3], w3, oa[px]))));
        }
    }

    // ---- NCHW store: lane = channel, 8 consecutive x (32 B/lane)
    float* op = out + ((size_t)b * 64 + l) * 16384 + y * 128 + x0w;
    f4 o0 = {oa[0], oa[1], oa[2], oa[3]};
    f4 o1 = {oa[4], oa[5], oa[6], oa[7]};
    *(f4*)op       = o0;
    *(f4*)(op + 4) = o1;
}

// ---------------------------------------------------------------------------
extern "C" void kernel_launch(void* const* d_in, const int* in_sizes, int n_in,
                              void* d_out, int out_size, void* d_ws, size_t ws_size,
                              hipStream_t stream) {
    const float* x1       = (const float*)d_in[0];
    const float* x2       = (const float*)d_in[1];
    const float* w_value  = (const float*)d_in[2];
    const float* b_value  = (const float*)d_in[3];
    const float* w_conv   = (const float*)d_in[4];
    const float* b_conv   = (const float*)d_in[5];
    const float* w_offset = (const float*)d_in[6];
    const float* b_offset = (const float*)d_in[7];
    const float* w_mask   = (const float*)d_in[8];
    const float* b_mask   = (const float*)d_in[9];
    const float* w_out    = (const float*)d_in[10];
    const float* b_out    = (const float*)d_in[11];

    float* vpad  = (float*)d_ws;
    char*  featb = (char*)d_ws + 17842176;
    char*  x2tp  = (char*)d_ws + 26230784;
    char*  wbfT  = (char*)d_ws + 34883584;
    char*  whead = (char*)d_ws + 34957312;
    float* outp  = (float*)d_out;

    hipLaunchKernelGGL(prep_zero_k,  dim3(325),  dim3(256), 0, stream, vpad, x2tp);
    hipLaunchKernelGGL(prep_w_k,     dim3(100),  dim3(256), 0, stream,
                       w_conv, w_offset, w_mask, wbfT, whead);
    hipLaunchKernelGGL(x2prep_k,     dim3(512),  dim3(256), 0, stream, x2, x2tp);
    hipLaunchKernelGGL(value_proj_k, dim3(1024), dim3(256), 0, stream,
                       x1, w_value, b_value, vpad);
    hipLaunchKernelGGL(conv_mfma_k,  dim3(1024), dim3(256), 0, stream,
                       x2tp, wbfT, b_conv, featb);
    hipLaunchKernelGGL(dcn_fused_v5, dim3(2048), dim3(256), 0, stream,
                       featb, vpad, whead, b_offset, b_mask, w_out, b_out, outp);
}